// Round 6
// baseline (455.399 us; speedup 1.0000x reference)
//
#include <hip/hip_runtime.h>

#define SEQ    2048
#define DM     2048
#define QKVN   3072
#define VTR    64

typedef short s16x8 __attribute__((ext_vector_type(8)));
typedef float f32x4 __attribute__((ext_vector_type(4)));
typedef unsigned short us;

#define MFMA(a,b,c) __builtin_amdgcn_mfma_f32_16x16x32_bf16((a),(b),(c),0,0,0)

__device__ __forceinline__ float bf2f(us u) {
    unsigned v = ((unsigned)u) << 16;
    return __builtin_bit_cast(float, v);
}
__device__ __forceinline__ us f2bf(float f) {
    unsigned u = __builtin_bit_cast(unsigned, f);
    u += 0x7FFFu + ((u >> 16) & 1u);
    return (us)(u >> 16);
}
// truncating bf16 store (folds to ds_write_b16_d16_hi) — R5-proven
__device__ __forceinline__ void stp(us* p, float f) {
    *p = (us)(__builtin_bit_cast(unsigned, f) >> 16);
}
__device__ __forceinline__ void glds16(const us* g, us* l) {
    __builtin_amdgcn_global_load_lds((__attribute__((address_space(1))) void*)g,
                                     (__attribute__((address_space(3))) void*)l, 16, 0, 0);
}

// ---------------------------------------------------------------------------
// Fused input/weight bf16 conversion. x -> xb (float4 idx 0..2097151);
// weights -> wqkvb..wob (contiguous 20 MiB region starting at wqkvb).
// ---------------------------------------------------------------------------
__global__ __launch_bounds__(256) void cvt_all(const float* __restrict__ x,
                                               const float* __restrict__ wq,
                                               const float* __restrict__ wk,
                                               const float* __restrict__ wv,
                                               const float* __restrict__ wo,
                                               us* __restrict__ xb,
                                               us* __restrict__ wdst) {
    int i = blockIdx.x * blockDim.x + threadIdx.x;   // total 4718592 float4s
    const float* src;
    int off;
    if (i < 2097152)      { src = x;  off = 0; }
    else {
        int j = i - 2097152;
        if (j < 1048576)      { src = wq; off = 2097152; }
        else if (j < 1310720) { src = wk; off = 2097152 + 1048576; }
        else if (j < 1572864) { src = wv; off = 2097152 + 1310720; }
        else                  { src = wo; off = 2097152 + 1572864; }
    }
    float4 v = ((const float4*)src)[i - off];
    ushort4 o;
    o.x = f2bf(v.x); o.y = f2bf(v.y); o.z = f2bf(v.z); o.w = f2bf(v.w);
    ((ushort4*)(i < 2097152 ? xb : wdst))[i < 2097152 ? i : i - 2097152] = o;
}

// ---------------------------------------------------------------------------
// GEMM m97-structure, 128x128 tile, BK=32, global_load_lds width-16 staging.
// ROPE=true: rotary on cols<2560 of the fused QKV output.
// ---------------------------------------------------------------------------
template <typename OutT, bool ROPE>
__global__ __launch_bounds__(256) void gemm_bt(const us* __restrict__ A, const us* __restrict__ W,
                                               OutT* __restrict__ C, int M, int N, int K) {
    __shared__ us la[128 * 32];
    __shared__ us lb[128 * 32];
    const int tid = threadIdx.x, lane = tid & 63, wave = tid >> 6;
    const int quad = lane >> 4, lr = lane & 15;
    const int m0 = blockIdx.x * 128, n0 = blockIdx.y * 128;
    const int wm = (wave & 1) * 64, wn = (wave >> 1) * 64;

    f32x4 acc[4][4] = {};

    const int r0 = wave * 32 + (lane >> 2);
    const int c0 = (lane & 3) * 8;
    const us* ga0 = A + (size_t)(m0 + r0) * K + c0;
    const us* ga1 = A + (size_t)(m0 + r0 + 16) * K + c0;
    const us* gb0 = W + (size_t)(n0 + r0) * K + c0;
    const us* gb1 = W + (size_t)(n0 + r0 + 16) * K + c0;
    us* lpa0 = &la[(wave * 32) * 32];
    us* lpa1 = &la[(wave * 32 + 16) * 32];
    us* lpb0 = &lb[(wave * 32) * 32];
    us* lpb1 = &lb[(wave * 32 + 16) * 32];

    for (int k0 = 0; k0 < K; k0 += 32) {
        glds16(ga0 + k0, lpa0);
        glds16(ga1 + k0, lpa1);
        glds16(gb0 + k0, lpb0);
        glds16(gb1 + k0, lpb1);
        __syncthreads();
        s16x8 af[4], bf[4];
#pragma unroll
        for (int i = 0; i < 4; i++) af[i] = *(const s16x8*)&la[(wm + i * 16 + lr) * 32 + quad * 8];
#pragma unroll
        for (int j = 0; j < 4; j++) bf[j] = *(const s16x8*)&lb[(wn + j * 16 + lr) * 32 + quad * 8];
#pragma unroll
        for (int i = 0; i < 4; i++)
#pragma unroll
            for (int j = 0; j < 4; j++)
                acc[i][j] = MFMA(af[i], bf[j], acc[i][j]);
        __syncthreads();
    }

#pragma unroll
    for (int i = 0; i < 4; i++)
#pragma unroll
        for (int j = 0; j < 4; j++)
#pragma unroll
            for (int r = 0; r < 4; r++) {
                int row = m0 + wm + i * 16 + quad * 4 + r;
                int col = n0 + wn + j * 16 + lr;
                float v = acc[i][j][r];
                if (ROPE && n0 < 2560) {
                    int pair = (col >> 1) & 31;
                    float inv = exp2f((float)pair * (-13.2877124f / 32.0f));
                    float ang = (float)(row & (SEQ - 1)) * inv;
                    float c = __cosf(ang), sn = __sinf(ang);
                    float p = __shfl_xor(v, 1);
                    v = v * c + ((col & 1) ? p * sn : -p * sn);
                }
                if constexpr (sizeof(OutT) == 2)
                    C[(size_t)row * N + col] = f2bf(v);
                else
                    C[(size_t)row * N + col] = v;
            }
}

// ---------------------------------------------------------------------------
// V transpose from fused qkv buffer (V at col 2560) -> vt (b,kvh, 64, S)
// ---------------------------------------------------------------------------
__global__ __launch_bounds__(256) void transpose_v(const us* __restrict__ qkv, us* __restrict__ vt) {
    __shared__ us tile[64][72];
    const int s0 = blockIdx.x * 64;
    const int bk = blockIdx.y;
    const int b = bk >> 3, kvh = bk & 7;
    const int t = threadIdx.x;
    const int r = t >> 3, cg = (t & 7) * 8;
#pragma unroll
    for (int p = 0; p < 2; p++) {
        int rr = r + p * 32;
        *(s16x8*)&tile[rr][cg] =
            *(const s16x8*)(qkv + (size_t)(b * SEQ + s0 + rr) * QKVN + 2560 + kvh * 64 + cg);
    }
    __syncthreads();
#pragma unroll
    for (int p = 0; p < 2; p++) {
        int d = r + p * 32;
        s16x8 val;
#pragma unroll
        for (int u = 0; u < 8; u++) val[u] = tile[cg + u][d];
        *(s16x8*)(vt + ((size_t)bk * VTR + d) * SEQ + s0 + cg) = val;
    }
}

// ---------------------------------------------------------------------------
// Causal flash attention — R6 4-tile structure + R11 delta: FULL-ITERATION
// register double-buffer of K AND V. Grid (8, B*H) = 512 blocks pins
// residency at 2 blocks/CU regardless of register use (per-SIMD budget
// 2 waves x <=1024 regs), so registers are free: kfA/vfA | kfB/vfB
// (+96 VGPR) and the next iteration's 16 K/V loads issue at the TOP of the
// current iteration -> ~4 kcy of cover instead of ~0.6-2 kcy. Rationale:
// issue accounting shows ~2.6 kcy/iter idle (VALU 1.26k, MFMA 0.58k of a
// 4.5 kcy iter) and the only big waits are vmcnt on kf/vf. In-loop waits
// become vmcnt(16) (16 newer outstanding), never a cold wait.
// Buffers are NAMED (A/B) with a x2-unrolled kb loop — runtime-indexed
// arrays would go to scratch (rule #20). R7/R8/R9 lesson: occupancy is
// grid/unified-RF-pinned; amortization + prefetch is what wins here.
// P-store scheme = R5-proven scalar stp + lgkmcnt(0). l via ones-col MFMA.
// ---------------------------------------------------------------------------
__global__ __launch_bounds__(256, 2) void flash_attn(const us* __restrict__ qkv,
                                                     const us* __restrict__ vt,
                                                     us* __restrict__ o) {
    __shared__ us P[4][4][16 * 72];           // [wave][tile]
    const int bh = blockIdx.y, b = bh >> 5, h = bh & 31, kvh = h >> 2;
    const int wave = threadIdx.x >> 6, lane = threadIdx.x & 63;
    const int quad = lane >> 4, lr = lane & 15;
    const int p = ((int)blockIdx.x + (int)(blockIdx.y >> 3)) & 7;
    const int qts[4] = {p, 15 - p, 16 + p, 31 - p};
    const us* kbase = qkv + (size_t)b * SEQ * QKVN + 2048 + kvh * 64;
    const us* vb = vt + (size_t)(b * 8 + kvh) * VTR * SEQ;
    const float QS = 0.125f * 1.44269504f;    // scale * log2(e)

    s16x8 onesb;
    const short ov = (lr == 0) ? (short)0x3F80 : (short)0;
#pragma unroll
    for (int j = 0; j < 8; j++) onesb[j] = ov;

    int q0[4];
    s16x8 qa[4][2];
#pragma unroll
    for (int t = 0; t < 4; t++) {
        q0[t] = qts[t] * 64 + wave * 16;
        const us* qb = qkv + (size_t)(b * SEQ + q0[t]) * QKVN + h * 64;
        qa[t][0] = *(const s16x8*)(qb + (size_t)lr * QKVN + quad * 8);
        qa[t][1] = *(const s16x8*)(qb + (size_t)lr * QKVN + 32 + quad * 8);
#pragma unroll
        for (int j = 0; j < 8; j++) {
            qa[t][0][j] = (short)f2bf(bf2f((us)qa[t][0][j]) * QS);
            qa[t][1][j] = (short)f2bf(bf2f((us)qa[t][1][j]) * QS);
        }
    }

    f32x4 oacc[4][5] = {};                    // per tile: [0..3]=O, [4] col0 = l

    // ---- load K and V fragments for one kb into named register buffers ----
    auto load_kv = [&](int kb, s16x8* kf, s16x8* vf) {
        const us* kp = kbase + (size_t)(kb * 64 + lr) * QKVN;
#pragma unroll
        for (int nb = 0; nb < 4; nb++) {
            kf[2 * nb]     = *(const s16x8*)(kp + (size_t)nb * 16 * QKVN + quad * 8);
            kf[2 * nb + 1] = *(const s16x8*)(kp + (size_t)nb * 16 * QKVN + 32 + quad * 8);
        }
#pragma unroll
        for (int n = 0; n < 4; n++)
#pragma unroll
            for (int kc = 0; kc < 2; kc++)
                vf[n * 2 + kc] = *(const s16x8*)(vb + (size_t)(n * 16 + lr) * SEQ +
                                                 kb * 64 + kc * 32 + quad * 8);
    };

    // QK for one tile -> sc; exp2 -> P[wave][t] (scalar b16 stores, R5-proven)
    auto qk_tile = [&](int t, f32x4* sc, const s16x8* kf) {
#pragma unroll
        for (int nb = 0; nb < 4; nb++) {
            sc[nb] = f32x4{0.f, 0.f, 0.f, 0.f};
            sc[nb] = MFMA(qa[t][0], kf[2 * nb], sc[nb]);
            sc[nb] = MFMA(qa[t][1], kf[2 * nb + 1], sc[nb]);
        }
    };
    auto store_tile = [&](int t, const f32x4* sc, int kb) {
        us* Pt = &P[wave][t][0];
        if (kb == qts[t]) {                   // diagonal block: causal mask
#pragma unroll
            for (int nb = 0; nb < 4; nb++)
#pragma unroll
                for (int r = 0; r < 4; r++) {
                    int key = kb * 64 + nb * 16 + lr, row = q0[t] + quad * 4 + r;
                    float s = (key > row) ? -1e30f : sc[nb][r];
                    stp(&Pt[(quad * 4 + r) * 72 + nb * 16 + lr], exp2f(s));
                }
        } else {
#pragma unroll
            for (int nb = 0; nb < 4; nb++)
#pragma unroll
                for (int r = 0; r < 4; r++)
                    stp(&Pt[(quad * 4 + r) * 72 + nb * 16 + lr], exp2f(sc[nb][r]));
        }
    };

    // one full iteration: QK all active tiles -> P stores -> PV (uses kf, vf)
    auto full_iter = [&](int kb, const s16x8* kf, const s16x8* vf) {
        const bool a0 = (kb <= qts[0]), a1 = (kb <= qts[1]), a2 = (kb <= qts[2]);
        f32x4 sa[4], sb[4];
        if (a0) qk_tile(0, sa, kf);
        if (a1) qk_tile(1, sb, kf);
        if (a0) store_tile(0, sa, kb);
        if (a1) store_tile(1, sb, kb);
        if (a2) qk_tile(2, sa, kf);
        qk_tile(3, sb, kf);                   // tile 3 always active
        if (a2) store_tile(2, sa, kb);
        store_tile(3, sb, kb);
        asm volatile("s_waitcnt lgkmcnt(0)" ::: "memory");   // wave-private tiles
        __builtin_amdgcn_s_setprio(1);
#pragma unroll
        for (int t = 0; t < 4; t++) {
            if (kb <= qts[t]) {
#pragma unroll
                for (int kc = 0; kc < 2; kc++) {
                    s16x8 pa = *(const s16x8*)&P[wave][t][lr * 72 + kc * 32 + quad * 8];
#pragma unroll
                    for (int n = 0; n < 4; n++)
                        oacc[t][n] = MFMA(pa, vf[n * 2 + kc], oacc[t][n]);
                    oacc[t][4] = MFMA(pa, onesb, oacc[t][4]);
                }
            }
        }
        __builtin_amdgcn_s_setprio(0);
    };

    s16x8 kfA[8], vfA[8], kfB[8], vfB[8];
    const int kbmax = qts[3];
    load_kv(0, kfA, vfA);
    for (int kb = 0; kb <= kbmax; kb += 2) {
        if (kb + 1 <= kbmax) load_kv(kb + 1, kfB, vfB);   // full-iter-ahead prefetch
        full_iter(kb, kfA, vfA);
        if (kb + 1 <= kbmax) {
            if (kb + 2 <= kbmax) load_kv(kb + 2, kfA, vfA);
            full_iter(kb + 1, kfB, vfB);
        }
    }

#pragma unroll
    for (int t = 0; t < 4; t++)
#pragma unroll
        for (int r = 0; r < 4; r++) {
            float l = __shfl(oacc[t][4][r], lane & 48);
            float li = 1.0f / l;
#pragma unroll
            for (int n = 0; n < 4; n++)
                o[(size_t)(b * SEQ + q0[t] + quad * 4 + r) * DM + h * 64 + n * 16 + lr] =
                    f2bf(oacc[t][n][r] * li);
        }
}

// ---------------------------------------------------------------------------
extern "C" void kernel_launch(void* const* d_in, const int* in_sizes, int n_in,
                              void* d_out, int out_size, void* d_ws, size_t ws_size,
                              hipStream_t stream) {
    const float* x  = (const float*)d_in[0];
    const float* wq = (const float*)d_in[1];
    const float* wk = (const float*)d_in[2];
    const float* wv = (const float*)d_in[3];
    const float* wo = (const float*)d_in[4];
    float* out = (float*)d_out;

    char* ws = (char*)d_ws;
    const size_t MB = 1024 * 1024;
    us* xb     = (us*)(ws + 0 * MB);    // 16 MiB; reused as abuf (flash out)
    us* abuf   = (us*)(ws + 0 * MB);
    us* wqkvb  = (us*)(ws + 16 * MB);   // 12 MiB (wq|wk|wv) — contiguous with wob
    us* wob    = (us*)(ws + 28 * MB);   // 8 MiB
    us* qkvbuf = (us*)(ws + 36 * MB);   // 24 MiB (4096 x 3072)
    us* vtbuf  = (us*)(ws + 60 * MB);   // 4 MiB

    dim3 blk(256);
    cvt_all<<<dim3(18432), blk, 0, stream>>>(x, wq, wk, wv, wo, xb, wqkvb);

    gemm_bt<us, true><<<dim3(32, 24), blk, 0, stream>>>(xb, wqkvb, qkvbuf, 4096, 3072, 2048);
    transpose_v<<<dim3(32, 16), blk, 0, stream>>>(qkvbuf, vtbuf);
    flash_attn<<<dim3(8, 64), blk, 0, stream>>>(qkvbuf, vtbuf, abuf);
    gemm_bt<float, false><<<dim3(32, 16), blk, 0, stream>>>(abuf, wob, out, 4096, 2048, 2048);
}

// Round 7
// 401.230 us; speedup vs baseline: 1.1350x; 1.1350x over previous
//
#include <hip/hip_runtime.h>

#define SEQ    2048
#define DM     2048
#define QKVN   3072
#define VTR    64

typedef short s16x8 __attribute__((ext_vector_type(8)));
typedef float f32x4 __attribute__((ext_vector_type(4)));
typedef unsigned short us;

#define MFMA(a,b,c) __builtin_amdgcn_mfma_f32_16x16x32_bf16((a),(b),(c),0,0,0)

__device__ __forceinline__ float bf2f(us u) {
    unsigned v = ((unsigned)u) << 16;
    return __builtin_bit_cast(float, v);
}
__device__ __forceinline__ us f2bf(float f) {
    unsigned u = __builtin_bit_cast(unsigned, f);
    u += 0x7FFFu + ((u >> 16) & 1u);
    return (us)(u >> 16);
}
// truncating bf16 store (folds to ds_write_b16_d16_hi) — R5-proven
__device__ __forceinline__ void stp(us* p, float f) {
    *p = (us)(__builtin_bit_cast(unsigned, f) >> 16);
}
__device__ __forceinline__ void glds16(const us* g, us* l) {
    __builtin_amdgcn_global_load_lds((__attribute__((address_space(1))) void*)g,
                                     (__attribute__((address_space(3))) void*)l, 16, 0, 0);
}

// ---------------------------------------------------------------------------
// Fused input/weight bf16 conversion. x -> xb (float4 idx 0..2097151);
// weights -> wqkvb..wob (contiguous 20 MiB region starting at wqkvb).
// ---------------------------------------------------------------------------
__global__ __launch_bounds__(256) void cvt_all(const float* __restrict__ x,
                                               const float* __restrict__ wq,
                                               const float* __restrict__ wk,
                                               const float* __restrict__ wv,
                                               const float* __restrict__ wo,
                                               us* __restrict__ xb,
                                               us* __restrict__ wdst) {
    int i = blockIdx.x * blockDim.x + threadIdx.x;   // total 4718592 float4s
    const float* src;
    int off;
    if (i < 2097152)      { src = x;  off = 0; }
    else {
        int j = i - 2097152;
        if (j < 1048576)      { src = wq; off = 2097152; }
        else if (j < 1310720) { src = wk; off = 2097152 + 1048576; }
        else if (j < 1572864) { src = wv; off = 2097152 + 1310720; }
        else                  { src = wo; off = 2097152 + 1572864; }
    }
    float4 v = ((const float4*)src)[i - off];
    ushort4 o;
    o.x = f2bf(v.x); o.y = f2bf(v.y); o.z = f2bf(v.z); o.w = f2bf(v.w);
    ((ushort4*)(i < 2097152 ? xb : wdst))[i < 2097152 ? i : i - 2097152] = o;
}

// ---------------------------------------------------------------------------
// RoPE cos/sin table: tab[pos*32 + pair] = {cos, sin} of pos * 10000^(-pair/32).
// Same __cosf/__sinf path as the old in-epilogue math -> bitwise identical.
// 2048*32 float2 = 512 KiB, written into the vtbuf region (dead until
// transpose_v, which runs after gemm1 has consumed the table).
// ---------------------------------------------------------------------------
__global__ __launch_bounds__(256) void rope_fill(float2* __restrict__ tab) {
    int i = blockIdx.x * blockDim.x + threadIdx.x;   // 65536
    int pos = i >> 5, pair = i & 31;
    float inv = exp2f((float)pair * (-13.2877124f / 32.0f));
    float ang = (float)pos * inv;
    tab[i] = float2{__cosf(ang), __sinf(ang)};
}

// ---------------------------------------------------------------------------
// GEMM m97-structure, 128x128 tile, BK=32, global_load_lds width-16 staging.
// ROPE=true: rotary on cols<2560 of the fused QKV output, via table lookup
// (R12: replaces exp2f+__sinf+__cosf per element — ~192 trans-pipe ops per
// thread — with one cached float2 load from the 512 KiB L2-resident table).
// ---------------------------------------------------------------------------
template <typename OutT, bool ROPE>
__global__ __launch_bounds__(256) void gemm_bt(const us* __restrict__ A, const us* __restrict__ W,
                                               OutT* __restrict__ C,
                                               const float2* __restrict__ rope_tab,
                                               int M, int N, int K) {
    __shared__ us la[128 * 32];
    __shared__ us lb[128 * 32];
    const int tid = threadIdx.x, lane = tid & 63, wave = tid >> 6;
    const int quad = lane >> 4, lr = lane & 15;
    const int m0 = blockIdx.x * 128, n0 = blockIdx.y * 128;
    const int wm = (wave & 1) * 64, wn = (wave >> 1) * 64;

    f32x4 acc[4][4] = {};

    const int r0 = wave * 32 + (lane >> 2);
    const int c0 = (lane & 3) * 8;
    const us* ga0 = A + (size_t)(m0 + r0) * K + c0;
    const us* ga1 = A + (size_t)(m0 + r0 + 16) * K + c0;
    const us* gb0 = W + (size_t)(n0 + r0) * K + c0;
    const us* gb1 = W + (size_t)(n0 + r0 + 16) * K + c0;
    us* lpa0 = &la[(wave * 32) * 32];
    us* lpa1 = &la[(wave * 32 + 16) * 32];
    us* lpb0 = &lb[(wave * 32) * 32];
    us* lpb1 = &lb[(wave * 32 + 16) * 32];

    for (int k0 = 0; k0 < K; k0 += 32) {
        glds16(ga0 + k0, lpa0);
        glds16(ga1 + k0, lpa1);
        glds16(gb0 + k0, lpb0);
        glds16(gb1 + k0, lpb1);
        __syncthreads();
        s16x8 af[4], bf[4];
#pragma unroll
        for (int i = 0; i < 4; i++) af[i] = *(const s16x8*)&la[(wm + i * 16 + lr) * 32 + quad * 8];
#pragma unroll
        for (int j = 0; j < 4; j++) bf[j] = *(const s16x8*)&lb[(wn + j * 16 + lr) * 32 + quad * 8];
#pragma unroll
        for (int i = 0; i < 4; i++)
#pragma unroll
            for (int j = 0; j < 4; j++)
                acc[i][j] = MFMA(af[i], bf[j], acc[i][j]);
        __syncthreads();
    }

#pragma unroll
    for (int i = 0; i < 4; i++)
#pragma unroll
        for (int j = 0; j < 4; j++)
#pragma unroll
            for (int r = 0; r < 4; r++) {
                int row = m0 + wm + i * 16 + quad * 4 + r;
                int col = n0 + wn + j * 16 + lr;
                float v = acc[i][j][r];
                if (ROPE && n0 < 2560) {
                    float2 cs = rope_tab[(row & (SEQ - 1)) * 32 + ((col >> 1) & 31)];
                    float p = __shfl_xor(v, 1);
                    v = v * cs.x + ((col & 1) ? p * cs.y : -p * cs.y);
                }
                if constexpr (sizeof(OutT) == 2)
                    C[(size_t)row * N + col] = f2bf(v);
                else
                    C[(size_t)row * N + col] = v;
            }
}

// ---------------------------------------------------------------------------
// V transpose from fused qkv buffer (V at col 2560) -> vt (b,kvh, 64, S)
// ---------------------------------------------------------------------------
__global__ __launch_bounds__(256) void transpose_v(const us* __restrict__ qkv, us* __restrict__ vt) {
    __shared__ us tile[64][72];
    const int s0 = blockIdx.x * 64;
    const int bk = blockIdx.y;
    const int b = bk >> 3, kvh = bk & 7;
    const int t = threadIdx.x;
    const int r = t >> 3, cg = (t & 7) * 8;
#pragma unroll
    for (int p = 0; p < 2; p++) {
        int rr = r + p * 32;
        *(s16x8*)&tile[rr][cg] =
            *(const s16x8*)(qkv + (size_t)(b * SEQ + s0 + rr) * QKVN + 2560 + kvh * 64 + cg);
    }
    __syncthreads();
#pragma unroll
    for (int p = 0; p < 2; p++) {
        int d = r + p * 32;
        s16x8 val;
#pragma unroll
        for (int u = 0; u < 8; u++) val[u] = tile[cg + u][d];
        *(s16x8*)(vt + ((size_t)bk * VTR + d) * SEQ + s0 + cg) = val;
    }
}

// ---------------------------------------------------------------------------
// Causal flash attention — R6 4-tile structure + R12 delta: ZERO-register
// V phase-shift. vf(kb+1) loads issue at the loop BOTTOM, right after PV
// consumes vf(kb) (same 32 regs, live range shifted one iteration), so the
// V wait at PV has a full QK+exp2+store phase (~2-4 kcy) of cover instead
// of ~0.5-1 kcy. Unified-RF budget (session-derived): 2 waves/SIMD cap is
// 256 VGPR+AGPR/wave; R6 ~200, R11's dual-buffer needed ~296 -> spilled
// 290 MB scratch. This version peaks ~215-230 -> fits. kf prefetch keeps
// its R6 slot (after last QK use). Grid (8, B*H) = 512 blocks; occupancy
// is RF-pinned at 2 waves/SIMD regardless (R7/R8/R9 evidence).
// P-store scheme = R5-proven scalar stp + lgkmcnt(0). l via ones-col MFMA.
// ---------------------------------------------------------------------------
__global__ __launch_bounds__(256, 2) void flash_attn(const us* __restrict__ qkv,
                                                     const us* __restrict__ vt,
                                                     us* __restrict__ o) {
    __shared__ us P[4][4][16 * 72];           // [wave][tile]
    const int bh = blockIdx.y, b = bh >> 5, h = bh & 31, kvh = h >> 2;
    const int wave = threadIdx.x >> 6, lane = threadIdx.x & 63;
    const int quad = lane >> 4, lr = lane & 15;
    const int p = ((int)blockIdx.x + (int)(blockIdx.y >> 3)) & 7;
    const int qts[4] = {p, 15 - p, 16 + p, 31 - p};
    const us* kbase = qkv + (size_t)b * SEQ * QKVN + 2048 + kvh * 64;
    const us* vb = vt + (size_t)(b * 8 + kvh) * VTR * SEQ;
    const float QS = 0.125f * 1.44269504f;    // scale * log2(e)

    s16x8 onesb;
    const short ov = (lr == 0) ? (short)0x3F80 : (short)0;
#pragma unroll
    for (int j = 0; j < 8; j++) onesb[j] = ov;

    int q0[4];
    s16x8 qa[4][2];
#pragma unroll
    for (int t = 0; t < 4; t++) {
        q0[t] = qts[t] * 64 + wave * 16;
        const us* qb = qkv + (size_t)(b * SEQ + q0[t]) * QKVN + h * 64;
        qa[t][0] = *(const s16x8*)(qb + (size_t)lr * QKVN + quad * 8);
        qa[t][1] = *(const s16x8*)(qb + (size_t)lr * QKVN + 32 + quad * 8);
#pragma unroll
        for (int j = 0; j < 8; j++) {
            qa[t][0][j] = (short)f2bf(bf2f((us)qa[t][0][j]) * QS);
            qa[t][1][j] = (short)f2bf(bf2f((us)qa[t][1][j]) * QS);
        }
    }

    f32x4 oacc[4][5] = {};                    // per tile: [0..3]=O, [4] col0 = l
    s16x8 kf[8], vf[8];
    {
        const us* kp = kbase + (size_t)lr * QKVN;
#pragma unroll
        for (int nb = 0; nb < 4; nb++) {
            kf[2 * nb]     = *(const s16x8*)(kp + (size_t)nb * 16 * QKVN + quad * 8);
            kf[2 * nb + 1] = *(const s16x8*)(kp + (size_t)nb * 16 * QKVN + 32 + quad * 8);
        }
#pragma unroll
        for (int n = 0; n < 4; n++)
#pragma unroll
            for (int kc = 0; kc < 2; kc++)
                vf[n * 2 + kc] = *(const s16x8*)(vb + (size_t)(n * 16 + lr) * SEQ +
                                                 kc * 32 + quad * 8);
    }

    // QK for one tile -> sc; exp2 -> P[wave][t] (scalar b16 stores, R5-proven)
    auto qk_tile = [&](int t, f32x4* sc) {
#pragma unroll
        for (int nb = 0; nb < 4; nb++) {
            sc[nb] = f32x4{0.f, 0.f, 0.f, 0.f};
            sc[nb] = MFMA(qa[t][0], kf[2 * nb], sc[nb]);
            sc[nb] = MFMA(qa[t][1], kf[2 * nb + 1], sc[nb]);
        }
    };
    auto store_tile = [&](int t, const f32x4* sc, int kb) {
        us* Pt = &P[wave][t][0];
        if (kb == qts[t]) {                   // diagonal block: causal mask
#pragma unroll
            for (int nb = 0; nb < 4; nb++)
#pragma unroll
                for (int r = 0; r < 4; r++) {
                    int key = kb * 64 + nb * 16 + lr, row = q0[t] + quad * 4 + r;
                    float s = (key > row) ? -1e30f : sc[nb][r];
                    stp(&Pt[(quad * 4 + r) * 72 + nb * 16 + lr], exp2f(s));
                }
        } else {
#pragma unroll
            for (int nb = 0; nb < 4; nb++)
#pragma unroll
                for (int r = 0; r < 4; r++)
                    stp(&Pt[(quad * 4 + r) * 72 + nb * 16 + lr], exp2f(sc[nb][r]));
        }
    };

    const int kbmax = qts[3];
    for (int kb = 0; kb <= kbmax; kb++) {
        const bool a0 = (kb <= qts[0]), a1 = (kb <= qts[1]), a2 = (kb <= qts[2]);
        f32x4 sa[4], sb[4];
        // ---- QK pair 1 (tiles 0,1) with current kf ----
        if (a0) qk_tile(0, sa);
        if (a1) qk_tile(1, sb);
        if (a0) store_tile(0, sa, kb);
        if (a1) store_tile(1, sb, kb);
        // ---- QK pair 2 (tiles 2,3) still with current kf ----
        if (a2) qk_tile(2, sa);
        qk_tile(3, sb);                       // tile 3 always active
        // ---- kf prefetch for kb+1 (kf now dead until next iteration) ----
        if (kb < kbmax) {
            const us* kp = kbase + (size_t)((kb + 1) * 64 + lr) * QKVN;
#pragma unroll
            for (int nb = 0; nb < 4; nb++) {
                kf[2 * nb]     = *(const s16x8*)(kp + (size_t)nb * 16 * QKVN + quad * 8);
                kf[2 * nb + 1] = *(const s16x8*)(kp + (size_t)nb * 16 * QKVN + 32 + quad * 8);
            }
        }
        if (a2) store_tile(2, sa, kb);
        store_tile(3, sb, kb);
        asm volatile("s_waitcnt lgkmcnt(0)" ::: "memory");   // wave-private tiles
        // ---- PV for all active tiles, shared vf (loaded one iter ahead) ----
        __builtin_amdgcn_s_setprio(1);
#pragma unroll
        for (int t = 0; t < 4; t++) {
            if (kb <= qts[t]) {
#pragma unroll
                for (int kc = 0; kc < 2; kc++) {
                    s16x8 pa = *(const s16x8*)&P[wave][t][lr * 72 + kc * 32 + quad * 8];
#pragma unroll
                    for (int n = 0; n < 4; n++)
                        oacc[t][n] = MFMA(pa, vf[n * 2 + kc], oacc[t][n]);
                    oacc[t][4] = MFMA(pa, onesb, oacc[t][4]);
                }
            }
        }
        __builtin_amdgcn_s_setprio(0);
        // ---- vf load for kb+1 (vf dead after PV; full next-QK-phase cover) ----
        if (kb < kbmax) {
#pragma unroll
            for (int n = 0; n < 4; n++)
#pragma unroll
                for (int kc = 0; kc < 2; kc++)
                    vf[n * 2 + kc] = *(const s16x8*)(vb + (size_t)(n * 16 + lr) * SEQ +
                                                     (kb + 1) * 64 + kc * 32 + quad * 8);
        }
    }

#pragma unroll
    for (int t = 0; t < 4; t++)
#pragma unroll
        for (int r = 0; r < 4; r++) {
            float l = __shfl(oacc[t][4][r], lane & 48);
            float li = 1.0f / l;
#pragma unroll
            for (int n = 0; n < 4; n++)
                o[(size_t)(b * SEQ + q0[t] + quad * 4 + r) * DM + h * 64 + n * 16 + lr] =
                    f2bf(oacc[t][n][r] * li);
        }
}

// ---------------------------------------------------------------------------
extern "C" void kernel_launch(void* const* d_in, const int* in_sizes, int n_in,
                              void* d_out, int out_size, void* d_ws, size_t ws_size,
                              hipStream_t stream) {
    const float* x  = (const float*)d_in[0];
    const float* wq = (const float*)d_in[1];
    const float* wk = (const float*)d_in[2];
    const float* wv = (const float*)d_in[3];
    const float* wo = (const float*)d_in[4];
    float* out = (float*)d_out;

    char* ws = (char*)d_ws;
    const size_t MB = 1024 * 1024;
    us* xb     = (us*)(ws + 0 * MB);    // 16 MiB; reused as abuf (flash out)
    us* abuf   = (us*)(ws + 0 * MB);
    us* wqkvb  = (us*)(ws + 16 * MB);   // 12 MiB (wq|wk|wv) — contiguous with wob
    us* wob    = (us*)(ws + 28 * MB);   // 8 MiB
    us* qkvbuf = (us*)(ws + 36 * MB);   // 24 MiB (4096 x 3072)
    us* vtbuf  = (us*)(ws + 60 * MB);   // 4 MiB
    float2* rtab = (float2*)(ws + 60 * MB);  // 512 KiB, temporal reuse of vtbuf:
                                             // written pre-gemm1, consumed by gemm1,
                                             // overwritten later by transpose_v

    dim3 blk(256);
    cvt_all<<<dim3(18432), blk, 0, stream>>>(x, wq, wk, wv, wo, xb, wqkvb);
    rope_fill<<<dim3(256), blk, 0, stream>>>(rtab);

    gemm_bt<us, true><<<dim3(32, 24), blk, 0, stream>>>(xb, wqkvb, qkvbuf, rtab, 4096, 3072, 2048);
    transpose_v<<<dim3(32, 16), blk, 0, stream>>>(qkvbuf, vtbuf);
    flash_attn<<<dim3(8, 64), blk, 0, stream>>>(qkvbuf, vtbuf, abuf);
    gemm_bt<float, false><<<dim3(32, 16), blk, 0, stream>>>(abuf, wob, out, nullptr, 4096, 2048, 2048);
}

// Round 8
// 384.143 us; speedup vs baseline: 1.1855x; 1.0445x over previous
//
#include <hip/hip_runtime.h>

#define SEQ    2048
#define DM     2048
#define QKVN   3072
#define VTR    64

typedef short s16x8 __attribute__((ext_vector_type(8)));
typedef float f32x4 __attribute__((ext_vector_type(4)));
typedef unsigned short us;

#define MFMA(a,b,c) __builtin_amdgcn_mfma_f32_16x16x32_bf16((a),(b),(c),0,0,0)

__device__ __forceinline__ float bf2f(us u) {
    unsigned v = ((unsigned)u) << 16;
    return __builtin_bit_cast(float, v);
}
__device__ __forceinline__ us f2bf(float f) {
    unsigned u = __builtin_bit_cast(unsigned, f);
    u += 0x7FFFu + ((u >> 16) & 1u);
    return (us)(u >> 16);
}
// truncating bf16 store (folds to ds_write_b16_d16_hi) — R5-proven
__device__ __forceinline__ void stp(us* p, float f) {
    *p = (us)(__builtin_bit_cast(unsigned, f) >> 16);
}
__device__ __forceinline__ void glds16(const us* g, us* l) {
    __builtin_amdgcn_global_load_lds((__attribute__((address_space(1))) void*)g,
                                     (__attribute__((address_space(3))) void*)l, 16, 0, 0);
}

// ---------------------------------------------------------------------------
// Fused input/weight bf16 conversion. x -> xb (float4 idx 0..2097151);
// weights -> wqkvb..wob (contiguous 20 MiB region starting at wqkvb).
// ---------------------------------------------------------------------------
__global__ __launch_bounds__(256) void cvt_all(const float* __restrict__ x,
                                               const float* __restrict__ wq,
                                               const float* __restrict__ wk,
                                               const float* __restrict__ wv,
                                               const float* __restrict__ wo,
                                               us* __restrict__ xb,
                                               us* __restrict__ wdst) {
    int i = blockIdx.x * blockDim.x + threadIdx.x;   // total 4718592 float4s
    const float* src;
    int off;
    if (i < 2097152)      { src = x;  off = 0; }
    else {
        int j = i - 2097152;
        if (j < 1048576)      { src = wq; off = 2097152; }
        else if (j < 1310720) { src = wk; off = 2097152 + 1048576; }
        else if (j < 1572864) { src = wv; off = 2097152 + 1310720; }
        else                  { src = wo; off = 2097152 + 1572864; }
    }
    float4 v = ((const float4*)src)[i - off];
    ushort4 o;
    o.x = f2bf(v.x); o.y = f2bf(v.y); o.z = f2bf(v.z); o.w = f2bf(v.w);
    ((ushort4*)(i < 2097152 ? xb : wdst))[i < 2097152 ? i : i - 2097152] = o;
}

// ---------------------------------------------------------------------------
// GEMM m97-structure, 128x128 tile, BK=32, global_load_lds width-16 staging.
// ROPE=true: rotary on cols<2560 of the fused QKV output — INLINE trig
// (R13: the R12 cos/sin table regressed gemm1 ~15-20us: 64 scattered 8-B
// table loads per thread in a 16%-occupancy epilogue are latency-exposed,
// while the TRANS-pipe trig was overlapped. Reverted to R10-proven form.)
// ---------------------------------------------------------------------------
template <typename OutT, bool ROPE>
__global__ __launch_bounds__(256) void gemm_bt(const us* __restrict__ A, const us* __restrict__ W,
                                               OutT* __restrict__ C, int M, int N, int K) {
    __shared__ us la[128 * 32];
    __shared__ us lb[128 * 32];
    const int tid = threadIdx.x, lane = tid & 63, wave = tid >> 6;
    const int quad = lane >> 4, lr = lane & 15;
    const int m0 = blockIdx.x * 128, n0 = blockIdx.y * 128;
    const int wm = (wave & 1) * 64, wn = (wave >> 1) * 64;

    f32x4 acc[4][4] = {};

    const int r0 = wave * 32 + (lane >> 2);
    const int c0 = (lane & 3) * 8;
    const us* ga0 = A + (size_t)(m0 + r0) * K + c0;
    const us* ga1 = A + (size_t)(m0 + r0 + 16) * K + c0;
    const us* gb0 = W + (size_t)(n0 + r0) * K + c0;
    const us* gb1 = W + (size_t)(n0 + r0 + 16) * K + c0;
    us* lpa0 = &la[(wave * 32) * 32];
    us* lpa1 = &la[(wave * 32 + 16) * 32];
    us* lpb0 = &lb[(wave * 32) * 32];
    us* lpb1 = &lb[(wave * 32 + 16) * 32];

    for (int k0 = 0; k0 < K; k0 += 32) {
        glds16(ga0 + k0, lpa0);
        glds16(ga1 + k0, lpa1);
        glds16(gb0 + k0, lpb0);
        glds16(gb1 + k0, lpb1);
        __syncthreads();
        s16x8 af[4], bf[4];
#pragma unroll
        for (int i = 0; i < 4; i++) af[i] = *(const s16x8*)&la[(wm + i * 16 + lr) * 32 + quad * 8];
#pragma unroll
        for (int j = 0; j < 4; j++) bf[j] = *(const s16x8*)&lb[(wn + j * 16 + lr) * 32 + quad * 8];
#pragma unroll
        for (int i = 0; i < 4; i++)
#pragma unroll
            for (int j = 0; j < 4; j++)
                acc[i][j] = MFMA(af[i], bf[j], acc[i][j]);
        __syncthreads();
    }

#pragma unroll
    for (int i = 0; i < 4; i++)
#pragma unroll
        for (int j = 0; j < 4; j++)
#pragma unroll
            for (int r = 0; r < 4; r++) {
                int row = m0 + wm + i * 16 + quad * 4 + r;
                int col = n0 + wn + j * 16 + lr;
                float v = acc[i][j][r];
                if (ROPE && n0 < 2560) {
                    int pair = (col >> 1) & 31;
                    float inv = exp2f((float)pair * (-13.2877124f / 32.0f));
                    float ang = (float)(row & (SEQ - 1)) * inv;
                    float c = __cosf(ang), sn = __sinf(ang);
                    float p = __shfl_xor(v, 1);
                    v = v * c + ((col & 1) ? p * sn : -p * sn);
                }
                if constexpr (sizeof(OutT) == 2)
                    C[(size_t)row * N + col] = f2bf(v);
                else
                    C[(size_t)row * N + col] = v;
            }
}

// ---------------------------------------------------------------------------
// V transpose from fused qkv buffer (V at col 2560) -> vt (b,kvh, 64, S)
// ---------------------------------------------------------------------------
__global__ __launch_bounds__(256) void transpose_v(const us* __restrict__ qkv, us* __restrict__ vt) {
    __shared__ us tile[64][72];
    const int s0 = blockIdx.x * 64;
    const int bk = blockIdx.y;
    const int b = bk >> 3, kvh = bk & 7;
    const int t = threadIdx.x;
    const int r = t >> 3, cg = (t & 7) * 8;
#pragma unroll
    for (int p = 0; p < 2; p++) {
        int rr = r + p * 32;
        *(s16x8*)&tile[rr][cg] =
            *(const s16x8*)(qkv + (size_t)(b * SEQ + s0 + rr) * QKVN + 2560 + kvh * 64 + cg);
    }
    __syncthreads();
#pragma unroll
    for (int p = 0; p < 2; p++) {
        int d = r + p * 32;
        s16x8 val;
#pragma unroll
        for (int u = 0; u < 8; u++) val[u] = tile[cg + u][d];
        *(s16x8*)(vt + ((size_t)bk * VTR + d) * SEQ + s0 + cg) = val;
    }
}

// ---------------------------------------------------------------------------
// Causal flash attention — R6 4-tile structure + R12's ZERO-register V
// phase-shift (kept for isolated measurement this round: with gemm1
// reverted, flash returns to the top of the dispatch table and its dur is
// a direct A/B vs R10's 123.5us). vf(kb+1) loads issue at the loop BOTTOM,
// right after PV consumes vf(kb) (same 32 regs, live range shifted one
// iteration) -> the V wait at PV has a full QK+exp2+store phase of cover.
// Unified-RF budget: 2 waves/SIMD cap is 256 VGPR+AGPR/wave; R6 ~200,
// R11's dual-buffer needed ~296 -> spilled. This version peaks ~215-230.
// Grid (8, B*H) = 512 blocks; occupancy RF-pinned at 2 waves/SIMD.
// P-store scheme = R5-proven scalar stp + lgkmcnt(0). l via ones-col MFMA.
// ---------------------------------------------------------------------------
__global__ __launch_bounds__(256, 2) void flash_attn(const us* __restrict__ qkv,
                                                     const us* __restrict__ vt,
                                                     us* __restrict__ o) {
    __shared__ us P[4][4][16 * 72];           // [wave][tile]
    const int bh = blockIdx.y, b = bh >> 5, h = bh & 31, kvh = h >> 2;
    const int wave = threadIdx.x >> 6, lane = threadIdx.x & 63;
    const int quad = lane >> 4, lr = lane & 15;
    const int p = ((int)blockIdx.x + (int)(blockIdx.y >> 3)) & 7;
    const int qts[4] = {p, 15 - p, 16 + p, 31 - p};
    const us* kbase = qkv + (size_t)b * SEQ * QKVN + 2048 + kvh * 64;
    const us* vb = vt + (size_t)(b * 8 + kvh) * VTR * SEQ;
    const float QS = 0.125f * 1.44269504f;    // scale * log2(e)

    s16x8 onesb;
    const short ov = (lr == 0) ? (short)0x3F80 : (short)0;
#pragma unroll
    for (int j = 0; j < 8; j++) onesb[j] = ov;

    int q0[4];
    s16x8 qa[4][2];
#pragma unroll
    for (int t = 0; t < 4; t++) {
        q0[t] = qts[t] * 64 + wave * 16;
        const us* qb = qkv + (size_t)(b * SEQ + q0[t]) * QKVN + h * 64;
        qa[t][0] = *(const s16x8*)(qb + (size_t)lr * QKVN + quad * 8);
        qa[t][1] = *(const s16x8*)(qb + (size_t)lr * QKVN + 32 + quad * 8);
#pragma unroll
        for (int j = 0; j < 8; j++) {
            qa[t][0][j] = (short)f2bf(bf2f((us)qa[t][0][j]) * QS);
            qa[t][1][j] = (short)f2bf(bf2f((us)qa[t][1][j]) * QS);
        }
    }

    f32x4 oacc[4][5] = {};                    // per tile: [0..3]=O, [4] col0 = l
    s16x8 kf[8], vf[8];
    {
        const us* kp = kbase + (size_t)lr * QKVN;
#pragma unroll
        for (int nb = 0; nb < 4; nb++) {
            kf[2 * nb]     = *(const s16x8*)(kp + (size_t)nb * 16 * QKVN + quad * 8);
            kf[2 * nb + 1] = *(const s16x8*)(kp + (size_t)nb * 16 * QKVN + 32 + quad * 8);
        }
#pragma unroll
        for (int n = 0; n < 4; n++)
#pragma unroll
            for (int kc = 0; kc < 2; kc++)
                vf[n * 2 + kc] = *(const s16x8*)(vb + (size_t)(n * 16 + lr) * SEQ +
                                                 kc * 32 + quad * 8);
    }

    // QK for one tile -> sc; exp2 -> P[wave][t] (scalar b16 stores, R5-proven)
    auto qk_tile = [&](int t, f32x4* sc) {
#pragma unroll
        for (int nb = 0; nb < 4; nb++) {
            sc[nb] = f32x4{0.f, 0.f, 0.f, 0.f};
            sc[nb] = MFMA(qa[t][0], kf[2 * nb], sc[nb]);
            sc[nb] = MFMA(qa[t][1], kf[2 * nb + 1], sc[nb]);
        }
    };
    auto store_tile = [&](int t, const f32x4* sc, int kb) {
        us* Pt = &P[wave][t][0];
        if (kb == qts[t]) {                   // diagonal block: causal mask
#pragma unroll
            for (int nb = 0; nb < 4; nb++)
#pragma unroll
                for (int r = 0; r < 4; r++) {
                    int key = kb * 64 + nb * 16 + lr, row = q0[t] + quad * 4 + r;
                    float s = (key > row) ? -1e30f : sc[nb][r];
                    stp(&Pt[(quad * 4 + r) * 72 + nb * 16 + lr], exp2f(s));
                }
        } else {
#pragma unroll
            for (int nb = 0; nb < 4; nb++)
#pragma unroll
                for (int r = 0; r < 4; r++)
                    stp(&Pt[(quad * 4 + r) * 72 + nb * 16 + lr], exp2f(sc[nb][r]));
        }
    };

    const int kbmax = qts[3];
    for (int kb = 0; kb <= kbmax; kb++) {
        const bool a0 = (kb <= qts[0]), a1 = (kb <= qts[1]), a2 = (kb <= qts[2]);
        f32x4 sa[4], sb[4];
        // ---- QK pair 1 (tiles 0,1) with current kf ----
        if (a0) qk_tile(0, sa);
        if (a1) qk_tile(1, sb);
        if (a0) store_tile(0, sa, kb);
        if (a1) store_tile(1, sb, kb);
        // ---- QK pair 2 (tiles 2,3) still with current kf ----
        if (a2) qk_tile(2, sa);
        qk_tile(3, sb);                       // tile 3 always active
        // ---- kf prefetch for kb+1 (kf now dead until next iteration) ----
        if (kb < kbmax) {
            const us* kp = kbase + (size_t)((kb + 1) * 64 + lr) * QKVN;
#pragma unroll
            for (int nb = 0; nb < 4; nb++) {
                kf[2 * nb]     = *(const s16x8*)(kp + (size_t)nb * 16 * QKVN + quad * 8);
                kf[2 * nb + 1] = *(const s16x8*)(kp + (size_t)nb * 16 * QKVN + 32 + quad * 8);
            }
        }
        if (a2) store_tile(2, sa, kb);
        store_tile(3, sb, kb);
        asm volatile("s_waitcnt lgkmcnt(0)" ::: "memory");   // wave-private tiles
        // ---- PV for all active tiles, shared vf (loaded one iter ahead) ----
        __builtin_amdgcn_s_setprio(1);
#pragma unroll
        for (int t = 0; t < 4; t++) {
            if (kb <= qts[t]) {
#pragma unroll
                for (int kc = 0; kc < 2; kc++) {
                    s16x8 pa = *(const s16x8*)&P[wave][t][lr * 72 + kc * 32 + quad * 8];
#pragma unroll
                    for (int n = 0; n < 4; n++)
                        oacc[t][n] = MFMA(pa, vf[n * 2 + kc], oacc[t][n]);
                    oacc[t][4] = MFMA(pa, onesb, oacc[t][4]);
                }
            }
        }
        __builtin_amdgcn_s_setprio(0);
        // ---- vf load for kb+1 (vf dead after PV; full next-QK-phase cover) ----
        if (kb < kbmax) {
#pragma unroll
            for (int n = 0; n < 4; n++)
#pragma unroll
                for (int kc = 0; kc < 2; kc++)
                    vf[n * 2 + kc] = *(const s16x8*)(vb + (size_t)(n * 16 + lr) * SEQ +
                                                     (kb + 1) * 64 + kc * 32 + quad * 8);
        }
    }

#pragma unroll
    for (int t = 0; t < 4; t++)
#pragma unroll
        for (int r = 0; r < 4; r++) {
            float l = __shfl(oacc[t][4][r], lane & 48);
            float li = 1.0f / l;
#pragma unroll
            for (int n = 0; n < 4; n++)
                o[(size_t)(b * SEQ + q0[t] + quad * 4 + r) * DM + h * 64 + n * 16 + lr] =
                    f2bf(oacc[t][n][r] * li);
        }
}

// ---------------------------------------------------------------------------
extern "C" void kernel_launch(void* const* d_in, const int* in_sizes, int n_in,
                              void* d_out, int out_size, void* d_ws, size_t ws_size,
                              hipStream_t stream) {
    const float* x  = (const float*)d_in[0];
    const float* wq = (const float*)d_in[1];
    const float* wk = (const float*)d_in[2];
    const float* wv = (const float*)d_in[3];
    const float* wo = (const float*)d_in[4];
    float* out = (float*)d_out;

    char* ws = (char*)d_ws;
    const size_t MB = 1024 * 1024;
    us* xb     = (us*)(ws + 0 * MB);    // 16 MiB; reused as abuf (flash out)
    us* abuf   = (us*)(ws + 0 * MB);
    us* wqkvb  = (us*)(ws + 16 * MB);   // 12 MiB (wq|wk|wv) — contiguous with wob
    us* wob    = (us*)(ws + 28 * MB);   // 8 MiB
    us* qkvbuf = (us*)(ws + 36 * MB);   // 24 MiB (4096 x 3072)
    us* vtbuf  = (us*)(ws + 60 * MB);   // 4 MiB

    dim3 blk(256);
    cvt_all<<<dim3(18432), blk, 0, stream>>>(x, wq, wk, wv, wo, xb, wqkvb);

    gemm_bt<us, true><<<dim3(32, 24), blk, 0, stream>>>(xb, wqkvb, qkvbuf, 4096, 3072, 2048);
    transpose_v<<<dim3(32, 16), blk, 0, stream>>>(qkvbuf, vtbuf);
    flash_attn<<<dim3(8, 64), blk, 0, stream>>>(qkvbuf, vtbuf, abuf);
    gemm_bt<float, false><<<dim3(32, 16), blk, 0, stream>>>(abuf, wob, out, 4096, 2048, 2048);
}

// Round 9
// 365.302 us; speedup vs baseline: 1.2466x; 1.0516x over previous
//
#include <hip/hip_runtime.h>

#define SEQ    2048
#define DM     2048
#define QKVN   3072
#define VTR    64

typedef short s16x8 __attribute__((ext_vector_type(8)));
typedef float f32x4 __attribute__((ext_vector_type(4)));
typedef unsigned short us;

#define MFMA(a,b,c) __builtin_amdgcn_mfma_f32_16x16x32_bf16((a),(b),(c),0,0,0)

__device__ __forceinline__ float bf2f(us u) {
    unsigned v = ((unsigned)u) << 16;
    return __builtin_bit_cast(float, v);
}
__device__ __forceinline__ us f2bf(float f) {
    unsigned u = __builtin_bit_cast(unsigned, f);
    u += 0x7FFFu + ((u >> 16) & 1u);
    return (us)(u >> 16);
}
// truncating bf16 store (folds to ds_write_b16_d16_hi) — R5-proven
__device__ __forceinline__ void stp(us* p, float f) {
    *p = (us)(__builtin_bit_cast(unsigned, f) >> 16);
}
__device__ __forceinline__ void glds16(const us* g, us* l) {
    __builtin_amdgcn_global_load_lds((__attribute__((address_space(1))) void*)g,
                                     (__attribute__((address_space(3))) void*)l, 16, 0, 0);
}

// ---------------------------------------------------------------------------
// Fused input/weight bf16 conversion. x -> xb (float4 idx 0..2097151);
// weights -> wqkvb..wob (contiguous 20 MiB region starting at wqkvb).
// ---------------------------------------------------------------------------
__global__ __launch_bounds__(256) void cvt_all(const float* __restrict__ x,
                                               const float* __restrict__ wq,
                                               const float* __restrict__ wk,
                                               const float* __restrict__ wv,
                                               const float* __restrict__ wo,
                                               us* __restrict__ xb,
                                               us* __restrict__ wdst) {
    int i = blockIdx.x * blockDim.x + threadIdx.x;   // total 4718592 float4s
    const float* src;
    int off;
    if (i < 2097152)      { src = x;  off = 0; }
    else {
        int j = i - 2097152;
        if (j < 1048576)      { src = wq; off = 2097152; }
        else if (j < 1310720) { src = wk; off = 2097152 + 1048576; }
        else if (j < 1572864) { src = wv; off = 2097152 + 1310720; }
        else                  { src = wo; off = 2097152 + 1572864; }
    }
    float4 v = ((const float4*)src)[i - off];
    ushort4 o;
    o.x = f2bf(v.x); o.y = f2bf(v.y); o.z = f2bf(v.z); o.w = f2bf(v.w);
    ((ushort4*)(i < 2097152 ? xb : wdst))[i < 2097152 ? i : i - 2097152] = o;
}

// ---------------------------------------------------------------------------
// GEMM m97-structure, 128x128 tile, BK=32, global_load_lds width-16 staging.
// R14: 2-phase LDS double-buffer (catalog T3-minimum). Old loop was 1-phase:
// glds16 -> barrier (full stage latency exposed) -> compute -> barrier.
// Now: stage(kt+1, cur^1) issues BEFORE computing buf[cur]; ONE barrier per
// iter (syncthreads drains vmcnt+lgkm -> stage complete + reads done); swap.
// Stage latency hides under the MFMA phase; barrier count halves.
// LDS 16->32 KiB (still >=3 blocks/CU at grid 768/512).
// ROPE=true: rotary on cols<2560 of fused QKV output — INLINE trig
// (R12's table lookup regressed: latency-exposed scattered loads in a
// 16%-occupancy epilogue; TRANS-pipe trig overlaps free).
// ---------------------------------------------------------------------------
template <typename OutT, bool ROPE>
__global__ __launch_bounds__(256) void gemm_bt(const us* __restrict__ A, const us* __restrict__ W,
                                               OutT* __restrict__ C, int M, int N, int K) {
    __shared__ us la[2][128 * 32];
    __shared__ us lb[2][128 * 32];
    const int tid = threadIdx.x, lane = tid & 63, wave = tid >> 6;
    const int quad = lane >> 4, lr = lane & 15;
    const int m0 = blockIdx.x * 128, n0 = blockIdx.y * 128;
    const int wm = (wave & 1) * 64, wn = (wave >> 1) * 64;

    f32x4 acc[4][4] = {};

    const int r0 = wave * 32 + (lane >> 2);
    const int c0 = (lane & 3) * 8;
    const us* ga0 = A + (size_t)(m0 + r0) * K + c0;
    const us* ga1 = A + (size_t)(m0 + r0 + 16) * K + c0;
    const us* gb0 = W + (size_t)(n0 + r0) * K + c0;
    const us* gb1 = W + (size_t)(n0 + r0 + 16) * K + c0;
    const int soff = (wave * 32) * 32;        // wave-uniform staging base (elems)

    auto stage = [&](int kt, int pb) {
        const int k0 = kt * 32;
        glds16(ga0 + k0, &la[pb][soff]);
        glds16(ga1 + k0, &la[pb][soff + 16 * 32]);
        glds16(gb0 + k0, &lb[pb][soff]);
        glds16(gb1 + k0, &lb[pb][soff + 16 * 32]);
    };

    const int NT = K / 32;
    stage(0, 0);
    __syncthreads();                          // drain stage 0
    int cur = 0;
    for (int kt = 0; kt < NT; ++kt) {
        if (kt + 1 < NT) stage(kt + 1, cur ^ 1);   // prefetch next tile (other buf)
        s16x8 af[4], bfr[4];
#pragma unroll
        for (int i = 0; i < 4; i++)
            af[i] = *(const s16x8*)&la[cur][(wm + i * 16 + lr) * 32 + quad * 8];
#pragma unroll
        for (int j = 0; j < 4; j++)
            bfr[j] = *(const s16x8*)&lb[cur][(wn + j * 16 + lr) * 32 + quad * 8];
#pragma unroll
        for (int i = 0; i < 4; i++)
#pragma unroll
            for (int j = 0; j < 4; j++)
                acc[i][j] = MFMA(af[i], bfr[j], acc[i][j]);
        __syncthreads();                      // stage(kt+1) complete; reads done
        cur ^= 1;
    }

#pragma unroll
    for (int i = 0; i < 4; i++)
#pragma unroll
        for (int j = 0; j < 4; j++)
#pragma unroll
            for (int r = 0; r < 4; r++) {
                int row = m0 + wm + i * 16 + quad * 4 + r;
                int col = n0 + wn + j * 16 + lr;
                float v = acc[i][j][r];
                if (ROPE && n0 < 2560) {
                    int pair = (col >> 1) & 31;
                    float inv = exp2f((float)pair * (-13.2877124f / 32.0f));
                    float ang = (float)(row & (SEQ - 1)) * inv;
                    float c = __cosf(ang), sn = __sinf(ang);
                    float p = __shfl_xor(v, 1);
                    v = v * c + ((col & 1) ? p * sn : -p * sn);
                }
                if constexpr (sizeof(OutT) == 2)
                    C[(size_t)row * N + col] = f2bf(v);
                else
                    C[(size_t)row * N + col] = v;
            }
}

// ---------------------------------------------------------------------------
// V transpose from fused qkv buffer (V at col 2560) -> vt (b,kvh, 64, S)
// ---------------------------------------------------------------------------
__global__ __launch_bounds__(256) void transpose_v(const us* __restrict__ qkv, us* __restrict__ vt) {
    __shared__ us tile[64][72];
    const int s0 = blockIdx.x * 64;
    const int bk = blockIdx.y;
    const int b = bk >> 3, kvh = bk & 7;
    const int t = threadIdx.x;
    const int r = t >> 3, cg = (t & 7) * 8;
#pragma unroll
    for (int p = 0; p < 2; p++) {
        int rr = r + p * 32;
        *(s16x8*)&tile[rr][cg] =
            *(const s16x8*)(qkv + (size_t)(b * SEQ + s0 + rr) * QKVN + 2560 + kvh * 64 + cg);
    }
    __syncthreads();
#pragma unroll
    for (int p = 0; p < 2; p++) {
        int d = r + p * 32;
        s16x8 val;
#pragma unroll
        for (int u = 0; u < 8; u++) val[u] = tile[cg + u][d];
        *(s16x8*)(vt + ((size_t)bk * VTR + d) * SEQ + s0 + cg) = val;
    }
}

// ---------------------------------------------------------------------------
// Causal flash attention — R6 4-tile structure + V phase-shift (R13-proven
// neutral-to-positive, kept). Occupancy RF-pinned at 2 waves/SIMD (unified
// VGPR+AGPR cap 256/wave; R6 ~200). kf prefetch after last QK use; vf(kb+1)
// at loop bottom after PV. Both K/V global-latency hypotheses measured null
// -> remaining idle is structural (dependent-MFMA latency + LDS round-trip
// at 2 waves/SIMD); fixing it = 8-warp 32x32 swapped-QK rewrite (future).
// P-store scheme = R5-proven scalar stp + lgkmcnt(0). l via ones-col MFMA.
// ---------------------------------------------------------------------------
__global__ __launch_bounds__(256, 2) void flash_attn(const us* __restrict__ qkv,
                                                     const us* __restrict__ vt,
                                                     us* __restrict__ o) {
    __shared__ us P[4][4][16 * 72];           // [wave][tile]
    const int bh = blockIdx.y, b = bh >> 5, h = bh & 31, kvh = h >> 2;
    const int wave = threadIdx.x >> 6, lane = threadIdx.x & 63;
    const int quad = lane >> 4, lr = lane & 15;
    const int p = ((int)blockIdx.x + (int)(blockIdx.y >> 3)) & 7;
    const int qts[4] = {p, 15 - p, 16 + p, 31 - p};
    const us* kbase = qkv + (size_t)b * SEQ * QKVN + 2048 + kvh * 64;
    const us* vb = vt + (size_t)(b * 8 + kvh) * VTR * SEQ;
    const float QS = 0.125f * 1.44269504f;    // scale * log2(e)

    s16x8 onesb;
    const short ov = (lr == 0) ? (short)0x3F80 : (short)0;
#pragma unroll
    for (int j = 0; j < 8; j++) onesb[j] = ov;

    int q0[4];
    s16x8 qa[4][2];
#pragma unroll
    for (int t = 0; t < 4; t++) {
        q0[t] = qts[t] * 64 + wave * 16;
        const us* qb = qkv + (size_t)(b * SEQ + q0[t]) * QKVN + h * 64;
        qa[t][0] = *(const s16x8*)(qb + (size_t)lr * QKVN + quad * 8);
        qa[t][1] = *(const s16x8*)(qb + (size_t)lr * QKVN + 32 + quad * 8);
#pragma unroll
        for (int j = 0; j < 8; j++) {
            qa[t][0][j] = (short)f2bf(bf2f((us)qa[t][0][j]) * QS);
            qa[t][1][j] = (short)f2bf(bf2f((us)qa[t][1][j]) * QS);
        }
    }

    f32x4 oacc[4][5] = {};                    // per tile: [0..3]=O, [4] col0 = l
    s16x8 kf[8], vf[8];
    {
        const us* kp = kbase + (size_t)lr * QKVN;
#pragma unroll
        for (int nb = 0; nb < 4; nb++) {
            kf[2 * nb]     = *(const s16x8*)(kp + (size_t)nb * 16 * QKVN + quad * 8);
            kf[2 * nb + 1] = *(const s16x8*)(kp + (size_t)nb * 16 * QKVN + 32 + quad * 8);
        }
#pragma unroll
        for (int n = 0; n < 4; n++)
#pragma unroll
            for (int kc = 0; kc < 2; kc++)
                vf[n * 2 + kc] = *(const s16x8*)(vb + (size_t)(n * 16 + lr) * SEQ +
                                                 kc * 32 + quad * 8);
    }

    // QK for one tile -> sc; exp2 -> P[wave][t] (scalar b16 stores, R5-proven)
    auto qk_tile = [&](int t, f32x4* sc) {
#pragma unroll
        for (int nb = 0; nb < 4; nb++) {
            sc[nb] = f32x4{0.f, 0.f, 0.f, 0.f};
            sc[nb] = MFMA(qa[t][0], kf[2 * nb], sc[nb]);
            sc[nb] = MFMA(qa[t][1], kf[2 * nb + 1], sc[nb]);
        }
    };
    auto store_tile = [&](int t, const f32x4* sc, int kb) {
        us* Pt = &P[wave][t][0];
        if (kb == qts[t]) {                   // diagonal block: causal mask
#pragma unroll
            for (int nb = 0; nb < 4; nb++)
#pragma unroll
                for (int r = 0; r < 4; r++) {
                    int key = kb * 64 + nb * 16 + lr, row = q0[t] + quad * 4 + r;
                    float s = (key > row) ? -1e30f : sc[nb][r];
                    stp(&Pt[(quad * 4 + r) * 72 + nb * 16 + lr], exp2f(s));
                }
        } else {
#pragma unroll
            for (int nb = 0; nb < 4; nb++)
#pragma unroll
                for (int r = 0; r < 4; r++)
                    stp(&Pt[(quad * 4 + r) * 72 + nb * 16 + lr], exp2f(sc[nb][r]));
        }
    };

    const int kbmax = qts[3];
    for (int kb = 0; kb <= kbmax; kb++) {
        const bool a0 = (kb <= qts[0]), a1 = (kb <= qts[1]), a2 = (kb <= qts[2]);
        f32x4 sa[4], sb[4];
        // ---- QK pair 1 (tiles 0,1) with current kf ----
        if (a0) qk_tile(0, sa);
        if (a1) qk_tile(1, sb);
        if (a0) store_tile(0, sa, kb);
        if (a1) store_tile(1, sb, kb);
        // ---- QK pair 2 (tiles 2,3) still with current kf ----
        if (a2) qk_tile(2, sa);
        qk_tile(3, sb);                       // tile 3 always active
        // ---- kf prefetch for kb+1 (kf now dead until next iteration) ----
        if (kb < kbmax) {
            const us* kp = kbase + (size_t)((kb + 1) * 64 + lr) * QKVN;
#pragma unroll
            for (int nb = 0; nb < 4; nb++) {
                kf[2 * nb]     = *(const s16x8*)(kp + (size_t)nb * 16 * QKVN + quad * 8);
                kf[2 * nb + 1] = *(const s16x8*)(kp + (size_t)nb * 16 * QKVN + 32 + quad * 8);
            }
        }
        if (a2) store_tile(2, sa, kb);
        store_tile(3, sb, kb);
        asm volatile("s_waitcnt lgkmcnt(0)" ::: "memory");   // wave-private tiles
        // ---- PV for all active tiles, shared vf (loaded one iter ahead) ----
        __builtin_amdgcn_s_setprio(1);
#pragma unroll
        for (int t = 0; t < 4; t++) {
            if (kb <= qts[t]) {
#pragma unroll
                for (int kc = 0; kc < 2; kc++) {
                    s16x8 pa = *(const s16x8*)&P[wave][t][lr * 72 + kc * 32 + quad * 8];
#pragma unroll
                    for (int n = 0; n < 4; n++)
                        oacc[t][n] = MFMA(pa, vf[n * 2 + kc], oacc[t][n]);
                    oacc[t][4] = MFMA(pa, onesb, oacc[t][4]);
                }
            }
        }
        __builtin_amdgcn_s_setprio(0);
        // ---- vf load for kb+1 (vf dead after PV; full next-QK-phase cover) ----
        if (kb < kbmax) {
#pragma unroll
            for (int n = 0; n < 4; n++)
#pragma unroll
                for (int kc = 0; kc < 2; kc++)
                    vf[n * 2 + kc] = *(const s16x8*)(vb + (size_t)(n * 16 + lr) * SEQ +
                                                     (kb + 1) * 64 + kc * 32 + quad * 8);
        }
    }

#pragma unroll
    for (int t = 0; t < 4; t++)
#pragma unroll
        for (int r = 0; r < 4; r++) {
            float l = __shfl(oacc[t][4][r], lane & 48);
            float li = 1.0f / l;
#pragma unroll
            for (int n = 0; n < 4; n++)
                o[(size_t)(b * SEQ + q0[t] + quad * 4 + r) * DM + h * 64 + n * 16 + lr] =
                    f2bf(oacc[t][n][r] * li);
        }
}

// ---------------------------------------------------------------------------
extern "C" void kernel_launch(void* const* d_in, const int* in_sizes, int n_in,
                              void* d_out, int out_size, void* d_ws, size_t ws_size,
                              hipStream_t stream) {
    const float* x  = (const float*)d_in[0];
    const float* wq = (const float*)d_in[1];
    const float* wk = (const float*)d_in[2];
    const float* wv = (const float*)d_in[3];
    const float* wo = (const float*)d_in[4];
    float* out = (float*)d_out;

    char* ws = (char*)d_ws;
    const size_t MB = 1024 * 1024;
    us* xb     = (us*)(ws + 0 * MB);    // 16 MiB; reused as abuf (flash out)
    us* abuf   = (us*)(ws + 0 * MB);
    us* wqkvb  = (us*)(ws + 16 * MB);   // 12 MiB (wq|wk|wv) — contiguous with wob
    us* wob    = (us*)(ws + 28 * MB);   // 8 MiB
    us* qkvbuf = (us*)(ws + 36 * MB);   // 24 MiB (4096 x 3072)
    us* vtbuf  = (us*)(ws + 60 * MB);   // 4 MiB

    dim3 blk(256);
    cvt_all<<<dim3(18432), blk, 0, stream>>>(x, wq, wk, wv, wo, xb, wqkvb);

    gemm_bt<us, true><<<dim3(32, 24), blk, 0, stream>>>(xb, wqkvb, qkvbuf, 4096, 3072, 2048);
    transpose_v<<<dim3(32, 16), blk, 0, stream>>>(qkvbuf, vtbuf);
    flash_attn<<<dim3(8, 64), blk, 0, stream>>>(qkvbuf, vtbuf, abuf);
    gemm_bt<float, false><<<dim3(32, 16), blk, 0, stream>>>(abuf, wob, out, 4096, 2048, 2048);
}

// Round 10
// 361.692 us; speedup vs baseline: 1.2591x; 1.0100x over previous
//
#include <hip/hip_runtime.h>

#define SEQ    2048
#define DM     2048
#define QKVN   3072
#define VTR    64

typedef short s16x8 __attribute__((ext_vector_type(8)));
typedef float f32x4 __attribute__((ext_vector_type(4)));
typedef unsigned short us;

#define MFMA(a,b,c) __builtin_amdgcn_mfma_f32_16x16x32_bf16((a),(b),(c),0,0,0)

__device__ __forceinline__ float bf2f(us u) {
    unsigned v = ((unsigned)u) << 16;
    return __builtin_bit_cast(float, v);
}
__device__ __forceinline__ us f2bf(float f) {
    unsigned u = __builtin_bit_cast(unsigned, f);
    u += 0x7FFFu + ((u >> 16) & 1u);
    return (us)(u >> 16);
}
// truncating bf16 store (folds to ds_write_b16_d16_hi) — R5-proven
__device__ __forceinline__ void stp(us* p, float f) {
    *p = (us)(__builtin_bit_cast(unsigned, f) >> 16);
}
__device__ __forceinline__ void glds16(const us* g, us* l) {
    __builtin_amdgcn_global_load_lds((__attribute__((address_space(1))) void*)g,
                                     (__attribute__((address_space(3))) void*)l, 16, 0, 0);
}

// ---------------------------------------------------------------------------
// Fused input/weight bf16 conversion. x -> xb (float4 idx 0..2097151);
// weights -> wqkvb..wob (contiguous 20 MiB region starting at wqkvb).
// ---------------------------------------------------------------------------
__global__ __launch_bounds__(256) void cvt_all(const float* __restrict__ x,
                                               const float* __restrict__ wq,
                                               const float* __restrict__ wk,
                                               const float* __restrict__ wv,
                                               const float* __restrict__ wo,
                                               us* __restrict__ xb,
                                               us* __restrict__ wdst) {
    int i = blockIdx.x * blockDim.x + threadIdx.x;   // total 4718592 float4s
    const float* src;
    int off;
    if (i < 2097152)      { src = x;  off = 0; }
    else {
        int j = i - 2097152;
        if (j < 1048576)      { src = wq; off = 2097152; }
        else if (j < 1310720) { src = wk; off = 2097152 + 1048576; }
        else if (j < 1572864) { src = wv; off = 2097152 + 1310720; }
        else                  { src = wo; off = 2097152 + 1572864; }
    }
    float4 v = ((const float4*)src)[i - off];
    ushort4 o;
    o.x = f2bf(v.x); o.y = f2bf(v.y); o.z = f2bf(v.z); o.w = f2bf(v.w);
    ((ushort4*)(i < 2097152 ? xb : wdst))[i < 2097152 ? i : i - 2097152] = o;
}

// ---------------------------------------------------------------------------
// R15 GEMM: 256x256 tile, BK=64, 512 threads (8 waves 2Mx4N), catalog
// 8-phase-family schedule as 4 phases/K-tile:
//   phase = { ds_read frag subtile | stage 1 half-tile (2x glds16) |
//             s_barrier | lgkmcnt(0) | setprio(1) 16 MFMA setprio(0) |
//             s_barrier }
// Counted vmcnt (T4): half-tile stream runs 5 ahead (prologue 5 halves);
// per tile t, phases 0-2 stage tile t+1's halves H1-3 (parity p^1, no
// hazard), phase 3 stages tile t+2's H0 (parity p — SAFE: all parity-p
// ds_reads retired by phase-2's lgkm+barrier); end-of-tile wait =
// vmcnt(2) (t+2's H0 stays in flight), vmcnt(0) only at the tail.
// RAW s_barrier everywhere (NOT __syncthreads — that drains vmcnt and
// kills the counted scheme). T2 swizzle both-sides (rule 21): linear
// glds16 dest + pre-swizzled SOURCE 16B-unit u^(row&7) + same XOR on
// ds_read addr => read(row,g) = G[row][g]; b128 reads tile all 32 banks.
// T5 setprio around each MFMA cluster (enabled regime here).
// LDS 128 KiB -> 1 block/CU, 2 waves/SIMD; VGPR budget irrelevant (<=512).
// ROPE=true: inline-trig rotary on cols<2560 (R12 table regressed).
// Requires: M%256==0, N%256==0, K%64==0, K/64 >= 3.
// ---------------------------------------------------------------------------
template <typename OutT, bool ROPE>
__global__ __launch_bounds__(512) void gemm_bt2(const us* __restrict__ A, const us* __restrict__ W,
                                                OutT* __restrict__ C, int M, int N, int K) {
    __shared__ us lA[2][2][128 * 64];         // [parity][half][row*64+col]  64 KiB
    __shared__ us lB[2][2][128 * 64];         // 64 KiB
    const int tid = threadIdx.x, lane = tid & 63, wave = tid >> 6;
    const int quad = lane >> 4, lr = lane & 15;
    const int mh = wave >> 2;                 // wave's A half (128-row group)
    const int wnx = wave & 3;                 // wave's 64-col group
    const int bh = wnx >> 1, br0 = (wnx & 1) * 64;
    const int m0 = blockIdx.x * 256, n0 = blockIdx.y * 256;

    // staging map: thread -> (row 0..63 [+64 on sweep 2], 16B-unit 0..7)
    const int srow = tid >> 3;
    const int scol = ((tid & 7) ^ (srow & 7)) * 8;   // pre-swizzled global col (elems)
    const int sdst = srow * 64 + (tid & 7) * 8;      // linear LDS dest (elems)

    const us* gA = A + (size_t)m0 * K;
    const us* gB = W + (size_t)n0 * K;

    // half-tile stream: s -> K-tile s>>2, type s&3 (0=A0,1=A1,2=B0,3=B1)
    auto stageH = [&](int s) {
        const int t = s >> 2, ty = s & 3, par = t & 1;
        const us* src;
        us* dst;
        if (ty < 2) { src = gA + (size_t)(ty * 128) * K;       dst = &lA[par][ty][0]; }
        else        { src = gB + (size_t)((ty - 2) * 128) * K; dst = &lB[par][ty - 2][0]; }
        src += t * 64;
        glds16(src + (size_t)srow * K + scol,        dst + sdst);
        glds16(src + (size_t)(srow + 64) * K + scol, dst + sdst + 64 * 64);
    };

    const int rsw = (lr & 7) << 3;            // read-side swizzle (elems); row&7 == lr&7
    auto rdA = [&](int par, int kk, int i) {
        return *(const s16x8*)&lA[par][mh][(i * 16 + lr) * 64 + ((kk * 32 + quad * 8) ^ rsw)];
    };
    auto rdB = [&](int par, int kk, int j) {
        return *(const s16x8*)&lB[par][bh][(br0 + j * 16 + lr) * 64 + ((kk * 32 + quad * 8) ^ rsw)];
    };

    f32x4 acc[8][4] = {};
    const int NT = K / 64;

    // prologue: tile0 all 4 halves + tile1 H0 -> wait all but newest half
    stageH(0); stageH(1); stageH(2); stageH(3); stageH(4);
    asm volatile("s_waitcnt vmcnt(2)" ::: "memory");
    __builtin_amdgcn_s_barrier();

    s16x8 af[2][4], ag[2][4], bfr[2][2], bg[2][2];
    for (int t = 0; t < NT; ++t) {
        const int par = t & 1;
        // ---- phase 0: (i 0-3) x (j 0-1) ----
#pragma unroll
        for (int kk = 0; kk < 2; kk++) {
#pragma unroll
            for (int i = 0; i < 4; i++) af[kk][i] = rdA(par, kk, i);
#pragma unroll
            for (int j = 0; j < 2; j++) bfr[kk][j] = rdB(par, kk, j);
        }
        if (t + 1 < NT) stageH(4 * (t + 1) + 1);
        __builtin_amdgcn_s_barrier();
        asm volatile("s_waitcnt lgkmcnt(0)" ::: "memory");
        __builtin_amdgcn_s_setprio(1);
#pragma unroll
        for (int i = 0; i < 4; i++)
#pragma unroll
            for (int j = 0; j < 2; j++)
#pragma unroll
                for (int kk = 0; kk < 2; kk++)
                    acc[i][j] = MFMA(af[kk][i], bfr[kk][j], acc[i][j]);
        __builtin_amdgcn_s_setprio(0);
        __builtin_amdgcn_s_barrier();
        // ---- phase 1: (i 0-3) x (j 2-3) ----
#pragma unroll
        for (int kk = 0; kk < 2; kk++)
#pragma unroll
            for (int j = 0; j < 2; j++) bg[kk][j] = rdB(par, kk, 2 + j);
        if (t + 1 < NT) stageH(4 * (t + 1) + 2);
        __builtin_amdgcn_s_barrier();
        asm volatile("s_waitcnt lgkmcnt(0)" ::: "memory");
        __builtin_amdgcn_s_setprio(1);
#pragma unroll
        for (int i = 0; i < 4; i++)
#pragma unroll
            for (int j = 0; j < 2; j++)
#pragma unroll
                for (int kk = 0; kk < 2; kk++)
                    acc[i][2 + j] = MFMA(af[kk][i], bg[kk][j], acc[i][2 + j]);
        __builtin_amdgcn_s_setprio(0);
        __builtin_amdgcn_s_barrier();
        // ---- phase 2: (i 4-7) x (j 0-1) ----
#pragma unroll
        for (int kk = 0; kk < 2; kk++)
#pragma unroll
            for (int i = 0; i < 4; i++) ag[kk][i] = rdA(par, kk, 4 + i);
        if (t + 1 < NT) stageH(4 * (t + 1) + 3);
        __builtin_amdgcn_s_barrier();
        asm volatile("s_waitcnt lgkmcnt(0)" ::: "memory");
        __builtin_amdgcn_s_setprio(1);
#pragma unroll
        for (int i = 0; i < 4; i++)
#pragma unroll
            for (int j = 0; j < 2; j++)
#pragma unroll
                for (int kk = 0; kk < 2; kk++)
                    acc[4 + i][j] = MFMA(ag[kk][i], bfr[kk][j], acc[4 + i][j]);
        __builtin_amdgcn_s_setprio(0);
        __builtin_amdgcn_s_barrier();
        // ---- phase 3: (i 4-7) x (j 2-3); stage t+2's H0 (parity par, safe) ----
        if (t + 2 < NT) stageH(4 * (t + 2));
        __builtin_amdgcn_s_setprio(1);
#pragma unroll
        for (int i = 0; i < 4; i++)
#pragma unroll
            for (int j = 0; j < 2; j++)
#pragma unroll
                for (int kk = 0; kk < 2; kk++)
                    acc[4 + i][2 + j] = MFMA(ag[kk][i], bg[kk][j], acc[4 + i][2 + j]);
        __builtin_amdgcn_s_setprio(0);
        if (t + 1 < NT) {
            if (t + 2 < NT) asm volatile("s_waitcnt vmcnt(2)" ::: "memory");
            else            asm volatile("s_waitcnt vmcnt(0)" ::: "memory");
            __builtin_amdgcn_s_barrier();
        }
    }

#pragma unroll
    for (int i = 0; i < 8; i++)
#pragma unroll
        for (int j = 0; j < 4; j++)
#pragma unroll
            for (int r = 0; r < 4; r++) {
                int row = m0 + mh * 128 + i * 16 + quad * 4 + r;
                int col = n0 + wnx * 64 + j * 16 + lr;
                float v = acc[i][j][r];
                if (ROPE && n0 < 2560) {
                    int pair = (col >> 1) & 31;
                    float inv = exp2f((float)pair * (-13.2877124f / 32.0f));
                    float ang = (float)(row & (SEQ - 1)) * inv;
                    float c = __cosf(ang), sn = __sinf(ang);
                    float p = __shfl_xor(v, 1);
                    v = v * c + ((col & 1) ? p * sn : -p * sn);
                }
                if constexpr (sizeof(OutT) == 2)
                    C[(size_t)row * N + col] = f2bf(v);
                else
                    C[(size_t)row * N + col] = v;
            }
}

// ---------------------------------------------------------------------------
// V transpose from fused qkv buffer (V at col 2560) -> vt (b,kvh, 64, S)
// ---------------------------------------------------------------------------
__global__ __launch_bounds__(256) void transpose_v(const us* __restrict__ qkv, us* __restrict__ vt) {
    __shared__ us tile[64][72];
    const int s0 = blockIdx.x * 64;
    const int bk = blockIdx.y;
    const int b = bk >> 3, kvh = bk & 7;
    const int t = threadIdx.x;
    const int r = t >> 3, cg = (t & 7) * 8;
#pragma unroll
    for (int p = 0; p < 2; p++) {
        int rr = r + p * 32;
        *(s16x8*)&tile[rr][cg] =
            *(const s16x8*)(qkv + (size_t)(b * SEQ + s0 + rr) * QKVN + 2560 + kvh * 64 + cg);
    }
    __syncthreads();
#pragma unroll
    for (int p = 0; p < 2; p++) {
        int d = r + p * 32;
        s16x8 val;
#pragma unroll
        for (int u = 0; u < 8; u++) val[u] = tile[cg + u][d];
        *(s16x8*)(vt + ((size_t)bk * VTR + d) * SEQ + s0 + cg) = val;
    }
}

// ---------------------------------------------------------------------------
// Causal flash attention — R6 4-tile structure + V phase-shift (R13-proven
// neutral, kept). Occupancy RF-pinned at 2 waves/SIMD (unified VGPR+AGPR
// cap 256/wave; this kernel ~200). kf prefetch after last QK use; vf(kb+1)
// at loop bottom after PV. Both K/V global-latency hypotheses measured null
// -> remaining idle is structural; fixing it = swapped-QK rewrite (future).
// P-store scheme = R5-proven scalar stp + lgkmcnt(0). l via ones-col MFMA.
// ---------------------------------------------------------------------------
__global__ __launch_bounds__(256, 2) void flash_attn(const us* __restrict__ qkv,
                                                     const us* __restrict__ vt,
                                                     us* __restrict__ o) {
    __shared__ us P[4][4][16 * 72];           // [wave][tile]
    const int bh = blockIdx.y, b = bh >> 5, h = bh & 31, kvh = h >> 2;
    const int wave = threadIdx.x >> 6, lane = threadIdx.x & 63;
    const int quad = lane >> 4, lr = lane & 15;
    const int p = ((int)blockIdx.x + (int)(blockIdx.y >> 3)) & 7;
    const int qts[4] = {p, 15 - p, 16 + p, 31 - p};
    const us* kbase = qkv + (size_t)b * SEQ * QKVN + 2048 + kvh * 64;
    const us* vb = vt + (size_t)(b * 8 + kvh) * VTR * SEQ;
    const float QS = 0.125f * 1.44269504f;    // scale * log2(e)

    s16x8 onesb;
    const short ov = (lr == 0) ? (short)0x3F80 : (short)0;
#pragma unroll
    for (int j = 0; j < 8; j++) onesb[j] = ov;

    int q0[4];
    s16x8 qa[4][2];
#pragma unroll
    for (int t = 0; t < 4; t++) {
        q0[t] = qts[t] * 64 + wave * 16;
        const us* qb = qkv + (size_t)(b * SEQ + q0[t]) * QKVN + h * 64;
        qa[t][0] = *(const s16x8*)(qb + (size_t)lr * QKVN + quad * 8);
        qa[t][1] = *(const s16x8*)(qb + (size_t)lr * QKVN + 32 + quad * 8);
#pragma unroll
        for (int j = 0; j < 8; j++) {
            qa[t][0][j] = (short)f2bf(bf2f((us)qa[t][0][j]) * QS);
            qa[t][1][j] = (short)f2bf(bf2f((us)qa[t][1][j]) * QS);
        }
    }

    f32x4 oacc[4][5] = {};                    // per tile: [0..3]=O, [4] col0 = l
    s16x8 kf[8], vf[8];
    {
        const us* kp = kbase + (size_t)lr * QKVN;
#pragma unroll
        for (int nb = 0; nb < 4; nb++) {
            kf[2 * nb]     = *(const s16x8*)(kp + (size_t)nb * 16 * QKVN + quad * 8);
            kf[2 * nb + 1] = *(const s16x8*)(kp + (size_t)nb * 16 * QKVN + 32 + quad * 8);
        }
#pragma unroll
        for (int n = 0; n < 4; n++)
#pragma unroll
            for (int kc = 0; kc < 2; kc++)
                vf[n * 2 + kc] = *(const s16x8*)(vb + (size_t)(n * 16 + lr) * SEQ +
                                                 kc * 32 + quad * 8);
    }

    // QK for one tile -> sc; exp2 -> P[wave][t] (scalar b16 stores, R5-proven)
    auto qk_tile = [&](int t, f32x4* sc) {
#pragma unroll
        for (int nb = 0; nb < 4; nb++) {
            sc[nb] = f32x4{0.f, 0.f, 0.f, 0.f};
            sc[nb] = MFMA(qa[t][0], kf[2 * nb], sc[nb]);
            sc[nb] = MFMA(qa[t][1], kf[2 * nb + 1], sc[nb]);
        }
    };
    auto store_tile = [&](int t, const f32x4* sc, int kb) {
        us* Pt = &P[wave][t][0];
        if (kb == qts[t]) {                   // diagonal block: causal mask
#pragma unroll
            for (int nb = 0; nb < 4; nb++)
#pragma unroll
                for (int r = 0; r < 4; r++) {
                    int key = kb * 64 + nb * 16 + lr, row = q0[t] + quad * 4 + r;
                    float s = (key > row) ? -1e30f : sc[nb][r];
                    stp(&Pt[(quad * 4 + r) * 72 + nb * 16 + lr], exp2f(s));
                }
        } else {
#pragma unroll
            for (int nb = 0; nb < 4; nb++)
#pragma unroll
                for (int r = 0; r < 4; r++)
                    stp(&Pt[(quad * 4 + r) * 72 + nb * 16 + lr], exp2f(sc[nb][r]));
        }
    };

    const int kbmax = qts[3];
    for (int kb = 0; kb <= kbmax; kb++) {
        const bool a0 = (kb <= qts[0]), a1 = (kb <= qts[1]), a2 = (kb <= qts[2]);
        f32x4 sa[4], sb[4];
        // ---- QK pair 1 (tiles 0,1) with current kf ----
        if (a0) qk_tile(0, sa);
        if (a1) qk_tile(1, sb);
        if (a0) store_tile(0, sa, kb);
        if (a1) store_tile(1, sb, kb);
        // ---- QK pair 2 (tiles 2,3) still with current kf ----
        if (a2) qk_tile(2, sa);
        qk_tile(3, sb);                       // tile 3 always active
        // ---- kf prefetch for kb+1 (kf now dead until next iteration) ----
        if (kb < kbmax) {
            const us* kp = kbase + (size_t)((kb + 1) * 64 + lr) * QKVN;
#pragma unroll
            for (int nb = 0; nb < 4; nb++) {
                kf[2 * nb]     = *(const s16x8*)(kp + (size_t)nb * 16 * QKVN + quad * 8);
                kf[2 * nb + 1] = *(const s16x8*)(kp + (size_t)nb * 16 * QKVN + 32 + quad * 8);
            }
        }
        if (a2) store_tile(2, sa, kb);
        store_tile(3, sb, kb);
        asm volatile("s_waitcnt lgkmcnt(0)" ::: "memory");   // wave-private tiles
        // ---- PV for all active tiles, shared vf (loaded one iter ahead) ----
        __builtin_amdgcn_s_setprio(1);
#pragma unroll
        for (int t = 0; t < 4; t++) {
            if (kb <= qts[t]) {
#pragma unroll
                for (int kc = 0; kc < 2; kc++) {
                    s16x8 pa = *(const s16x8*)&P[wave][t][lr * 72 + kc * 32 + quad * 8];
#pragma unroll
                    for (int n = 0; n < 4; n++)
                        oacc[t][n] = MFMA(pa, vf[n * 2 + kc], oacc[t][n]);
                    oacc[t][4] = MFMA(pa, onesb, oacc[t][4]);
                }
            }
        }
        __builtin_amdgcn_s_setprio(0);
        // ---- vf load for kb+1 (vf dead after PV; full next-QK-phase cover) ----
        if (kb < kbmax) {
#pragma unroll
            for (int n = 0; n < 4; n++)
#pragma unroll
                for (int kc = 0; kc < 2; kc++)
                    vf[n * 2 + kc] = *(const s16x8*)(vb + (size_t)(n * 16 + lr) * SEQ +
                                                     (kb + 1) * 64 + kc * 32 + quad * 8);
        }
    }

#pragma unroll
    for (int t = 0; t < 4; t++)
#pragma unroll
        for (int r = 0; r < 4; r++) {
            float l = __shfl(oacc[t][4][r], lane & 48);
            float li = 1.0f / l;
#pragma unroll
            for (int n = 0; n < 4; n++)
                o[(size_t)(b * SEQ + q0[t] + quad * 4 + r) * DM + h * 64 + n * 16 + lr] =
                    f2bf(oacc[t][n][r] * li);
        }
}

// ---------------------------------------------------------------------------
extern "C" void kernel_launch(void* const* d_in, const int* in_sizes, int n_in,
                              void* d_out, int out_size, void* d_ws, size_t ws_size,
                              hipStream_t stream) {
    const float* x  = (const float*)d_in[0];
    const float* wq = (const float*)d_in[1];
    const float* wk = (const float*)d_in[2];
    const float* wv = (const float*)d_in[3];
    const float* wo = (const float*)d_in[4];
    float* out = (float*)d_out;

    char* ws = (char*)d_ws;
    const size_t MB = 1024 * 1024;
    us* xb     = (us*)(ws + 0 * MB);    // 16 MiB; reused as abuf (flash out)
    us* abuf   = (us*)(ws + 0 * MB);
    us* wqkvb  = (us*)(ws + 16 * MB);   // 12 MiB (wq|wk|wv) — contiguous with wob
    us* wob    = (us*)(ws + 28 * MB);   // 8 MiB
    us* qkvbuf = (us*)(ws + 36 * MB);   // 24 MiB (4096 x 3072)
    us* vtbuf  = (us*)(ws + 60 * MB);   // 4 MiB

    dim3 blk(256);
    cvt_all<<<dim3(18432), blk, 0, stream>>>(x, wq, wk, wv, wo, xb, wqkvb);

    gemm_bt2<us, true><<<dim3(16, 12), dim3(512), 0, stream>>>(xb, wqkvb, qkvbuf, 4096, 3072, 2048);
    transpose_v<<<dim3(32, 16), blk, 0, stream>>>(qkvbuf, vtbuf);
    flash_attn<<<dim3(8, 64), blk, 0, stream>>>(qkvbuf, vtbuf, abuf);
    gemm_bt2<float, false><<<dim3(16, 8), dim3(512), 0, stream>>>(abuf, wob, out, 4096, 2048, 2048);
}

// Round 11
// 344.125 us; speedup vs baseline: 1.3234x; 1.0510x over previous
//
#include <hip/hip_runtime.h>

#define SEQ    2048
#define DM     2048
#define QKVN   3072
#define VTR    64

typedef short s16x8 __attribute__((ext_vector_type(8)));
typedef float f32x4 __attribute__((ext_vector_type(4)));
typedef unsigned short us;

#define MFMA(a,b,c) __builtin_amdgcn_mfma_f32_16x16x32_bf16((a),(b),(c),0,0,0)

__device__ __forceinline__ float bf2f(us u) {
    unsigned v = ((unsigned)u) << 16;
    return __builtin_bit_cast(float, v);
}
__device__ __forceinline__ us f2bf(float f) {
    unsigned u = __builtin_bit_cast(unsigned, f);
    u += 0x7FFFu + ((u >> 16) & 1u);
    return (us)(u >> 16);
}
// truncating bf16 store (folds to ds_write_b16_d16_hi) — R5-proven
__device__ __forceinline__ void stp(us* p, float f) {
    *p = (us)(__builtin_bit_cast(unsigned, f) >> 16);
}
__device__ __forceinline__ void glds16(const us* g, us* l) {
    __builtin_amdgcn_global_load_lds((__attribute__((address_space(1))) void*)g,
                                     (__attribute__((address_space(3))) void*)l, 16, 0, 0);
}

// ---------------------------------------------------------------------------
// Fused input/weight bf16 conversion. x -> xb (float4 idx 0..2097151);
// weights -> wqkvb..wob (contiguous 20 MiB region starting at wqkvb).
// ---------------------------------------------------------------------------
__global__ __launch_bounds__(256) void cvt_all(const float* __restrict__ x,
                                               const float* __restrict__ wq,
                                               const float* __restrict__ wk,
                                               const float* __restrict__ wv,
                                               const float* __restrict__ wo,
                                               us* __restrict__ xb,
                                               us* __restrict__ wdst) {
    int i = blockIdx.x * blockDim.x + threadIdx.x;   // total 4718592 float4s
    const float* src;
    int off;
    if (i < 2097152)      { src = x;  off = 0; }
    else {
        int j = i - 2097152;
        if (j < 1048576)      { src = wq; off = 2097152; }
        else if (j < 1310720) { src = wk; off = 2097152 + 1048576; }
        else if (j < 1572864) { src = wv; off = 2097152 + 1310720; }
        else                  { src = wo; off = 2097152 + 1572864; }
    }
    float4 v = ((const float4*)src)[i - off];
    ushort4 o;
    o.x = f2bf(v.x); o.y = f2bf(v.y); o.z = f2bf(v.z); o.w = f2bf(v.w);
    ((ushort4*)(i < 2097152 ? xb : wdst))[i < 2097152 ? i : i - 2097152] = o;
}

// ---------------------------------------------------------------------------
// R15 GEMM (validated round 10): 256x256 tile, BK=64, 512 threads (8 waves
// 2Mx4N), 4 phases/K-tile, counted vmcnt (never 0 mid-loop), raw s_barrier,
// both-sides swizzle, T5 setprio. See round-10 notes. Used for gemm1
// (N=3072 -> grid 192, 75% CU fill — best available N-decomposition).
// ---------------------------------------------------------------------------
template <typename OutT, bool ROPE>
__global__ __launch_bounds__(512) void gemm_bt2(const us* __restrict__ A, const us* __restrict__ W,
                                                OutT* __restrict__ C, int M, int N, int K) {
    __shared__ us lA[2][2][128 * 64];         // [parity][half][row*64+col]  64 KiB
    __shared__ us lB[2][2][128 * 64];         // 64 KiB
    const int tid = threadIdx.x, lane = tid & 63, wave = tid >> 6;
    const int quad = lane >> 4, lr = lane & 15;
    const int mh = wave >> 2;                 // wave's A half (128-row group)
    const int wnx = wave & 3;                 // wave's 64-col group
    const int bh = wnx >> 1, br0 = (wnx & 1) * 64;
    const int m0 = blockIdx.x * 256, n0 = blockIdx.y * 256;

    const int srow = tid >> 3;
    const int scol = ((tid & 7) ^ (srow & 7)) * 8;   // pre-swizzled global col (elems)
    const int sdst = srow * 64 + (tid & 7) * 8;      // linear LDS dest (elems)

    const us* gA = A + (size_t)m0 * K;
    const us* gB = W + (size_t)n0 * K;

    auto stageH = [&](int s) {
        const int t = s >> 2, ty = s & 3, par = t & 1;
        const us* src;
        us* dst;
        if (ty < 2) { src = gA + (size_t)(ty * 128) * K;       dst = &lA[par][ty][0]; }
        else        { src = gB + (size_t)((ty - 2) * 128) * K; dst = &lB[par][ty - 2][0]; }
        src += t * 64;
        glds16(src + (size_t)srow * K + scol,        dst + sdst);
        glds16(src + (size_t)(srow + 64) * K + scol, dst + sdst + 64 * 64);
    };

    const int rsw = (lr & 7) << 3;            // read-side swizzle (elems); row&7 == lr&7
    auto rdA = [&](int par, int kk, int i) {
        return *(const s16x8*)&lA[par][mh][(i * 16 + lr) * 64 + ((kk * 32 + quad * 8) ^ rsw)];
    };
    auto rdB = [&](int par, int kk, int j) {
        return *(const s16x8*)&lB[par][bh][(br0 + j * 16 + lr) * 64 + ((kk * 32 + quad * 8) ^ rsw)];
    };

    f32x4 acc[8][4] = {};
    const int NT = K / 64;

    stageH(0); stageH(1); stageH(2); stageH(3); stageH(4);
    asm volatile("s_waitcnt vmcnt(2)" ::: "memory");
    __builtin_amdgcn_s_barrier();

    s16x8 af[2][4], ag[2][4], bfr[2][2], bg[2][2];
    for (int t = 0; t < NT; ++t) {
        const int par = t & 1;
        // ---- phase 0: (i 0-3) x (j 0-1) ----
#pragma unroll
        for (int kk = 0; kk < 2; kk++) {
#pragma unroll
            for (int i = 0; i < 4; i++) af[kk][i] = rdA(par, kk, i);
#pragma unroll
            for (int j = 0; j < 2; j++) bfr[kk][j] = rdB(par, kk, j);
        }
        if (t + 1 < NT) stageH(4 * (t + 1) + 1);
        __builtin_amdgcn_s_barrier();
        asm volatile("s_waitcnt lgkmcnt(0)" ::: "memory");
        __builtin_amdgcn_s_setprio(1);
#pragma unroll
        for (int i = 0; i < 4; i++)
#pragma unroll
            for (int j = 0; j < 2; j++)
#pragma unroll
                for (int kk = 0; kk < 2; kk++)
                    acc[i][j] = MFMA(af[kk][i], bfr[kk][j], acc[i][j]);
        __builtin_amdgcn_s_setprio(0);
        __builtin_amdgcn_s_barrier();
        // ---- phase 1: (i 0-3) x (j 2-3) ----
#pragma unroll
        for (int kk = 0; kk < 2; kk++)
#pragma unroll
            for (int j = 0; j < 2; j++) bg[kk][j] = rdB(par, kk, 2 + j);
        if (t + 1 < NT) stageH(4 * (t + 1) + 2);
        __builtin_amdgcn_s_barrier();
        asm volatile("s_waitcnt lgkmcnt(0)" ::: "memory");
        __builtin_amdgcn_s_setprio(1);
#pragma unroll
        for (int i = 0; i < 4; i++)
#pragma unroll
            for (int j = 0; j < 2; j++)
#pragma unroll
                for (int kk = 0; kk < 2; kk++)
                    acc[i][2 + j] = MFMA(af[kk][i], bg[kk][j], acc[i][2 + j]);
        __builtin_amdgcn_s_setprio(0);
        __builtin_amdgcn_s_barrier();
        // ---- phase 2: (i 4-7) x (j 0-1) ----
#pragma unroll
        for (int kk = 0; kk < 2; kk++)
#pragma unroll
            for (int i = 0; i < 4; i++) ag[kk][i] = rdA(par, kk, 4 + i);
        if (t + 1 < NT) stageH(4 * (t + 1) + 3);
        __builtin_amdgcn_s_barrier();
        asm volatile("s_waitcnt lgkmcnt(0)" ::: "memory");
        __builtin_amdgcn_s_setprio(1);
#pragma unroll
        for (int i = 0; i < 4; i++)
#pragma unroll
            for (int j = 0; j < 2; j++)
#pragma unroll
                for (int kk = 0; kk < 2; kk++)
                    acc[4 + i][j] = MFMA(ag[kk][i], bfr[kk][j], acc[4 + i][j]);
        __builtin_amdgcn_s_setprio(0);
        __builtin_amdgcn_s_barrier();
        // ---- phase 3: (i 4-7) x (j 2-3); stage t+2's H0 (parity par, safe) ----
        if (t + 2 < NT) stageH(4 * (t + 2));
        __builtin_amdgcn_s_setprio(1);
#pragma unroll
        for (int i = 0; i < 4; i++)
#pragma unroll
            for (int j = 0; j < 2; j++)
#pragma unroll
                for (int kk = 0; kk < 2; kk++)
                    acc[4 + i][2 + j] = MFMA(ag[kk][i], bg[kk][j], acc[4 + i][2 + j]);
        __builtin_amdgcn_s_setprio(0);
        if (t + 1 < NT) {
            if (t + 2 < NT) asm volatile("s_waitcnt vmcnt(2)" ::: "memory");
            else            asm volatile("s_waitcnt vmcnt(0)" ::: "memory");
            __builtin_amdgcn_s_barrier();
        }
    }

#pragma unroll
    for (int i = 0; i < 8; i++)
#pragma unroll
        for (int j = 0; j < 4; j++)
#pragma unroll
            for (int r = 0; r < 4; r++) {
                int row = m0 + mh * 128 + i * 16 + quad * 4 + r;
                int col = n0 + wnx * 64 + j * 16 + lr;
                float v = acc[i][j][r];
                if (ROPE && n0 < 2560) {
                    int pair = (col >> 1) & 31;
                    float inv = exp2f((float)pair * (-13.2877124f / 32.0f));
                    float ang = (float)(row & (SEQ - 1)) * inv;
                    float c = __cosf(ang), sn = __sinf(ang);
                    float p = __shfl_xor(v, 1);
                    v = v * c + ((col & 1) ? p * sn : -p * sn);
                }
                if constexpr (sizeof(OutT) == 2)
                    C[(size_t)row * N + col] = f2bf(v);
                else
                    C[(size_t)row * N + col] = v;
            }
}

// ---------------------------------------------------------------------------
// R16 GEMM: 256x128 tile (BN=128) — same validated R15 schedule, retiled so
// gemm2's grid is (16,16)=256 blocks = 100% CU fill (was 128 = 50%).
// 8 waves 2Mx4N: per-wave 128x32 output (acc[8][2]). B = single 128-row
// half (32 KiB); LDS total 96 KiB. Stream = 3 halves/tile {A0,A1,B}:
// ph0 stages t+1.A1, ph1 stages t+1.B then t+2.A0 (parity par — safe:
// A0[par] reads retired by ph0's post-barrier), end wait vmcnt(2) keeps
// t+2.A0 in flight (vmcnt(0) only at the tail). Same barrier/lgkm/setprio
// placement as gemm_bt2 — sync structure inherited, parameters changed.
// Requires: M%256==0, N%128==0, K%64==0, K/64 >= 3.
// ---------------------------------------------------------------------------
template <typename OutT>
__global__ __launch_bounds__(512) void gemm_bt2n(const us* __restrict__ A, const us* __restrict__ W,
                                                 OutT* __restrict__ C, int M, int N, int K) {
    __shared__ us lA[2][2][128 * 64];         // 64 KiB
    __shared__ us lB[2][128 * 64];            // 32 KiB
    const int tid = threadIdx.x, lane = tid & 63, wave = tid >> 6;
    const int quad = lane >> 4, lr = lane & 15;
    const int mh = wave >> 2;                 // wave's A half (128-row group)
    const int wnx = wave & 3;                 // wave's 32-col group
    const int m0 = blockIdx.x * 256, n0 = blockIdx.y * 128;

    const int srow = tid >> 3;
    const int scol = ((tid & 7) ^ (srow & 7)) * 8;
    const int sdst = srow * 64 + (tid & 7) * 8;

    const us* gA = A + (size_t)m0 * K;
    const us* gB = W + (size_t)n0 * K;

    // ty: 0=A0, 1=A1, 2=B
    auto stageH = [&](int t, int ty) {
        const int par = t & 1;
        const us* src;
        us* dst;
        if (ty < 2) { src = gA + (size_t)(ty * 128) * K; dst = &lA[par][ty][0]; }
        else        { src = gB;                           dst = &lB[par][0]; }
        src += t * 64;
        glds16(src + (size_t)srow * K + scol,        dst + sdst);
        glds16(src + (size_t)(srow + 64) * K + scol, dst + sdst + 64 * 64);
    };

    const int rsw = (lr & 7) << 3;
    auto rdA = [&](int par, int kk, int i) {
        return *(const s16x8*)&lA[par][mh][(i * 16 + lr) * 64 + ((kk * 32 + quad * 8) ^ rsw)];
    };
    auto rdB = [&](int par, int kk, int j) {
        return *(const s16x8*)&lB[par][(wnx * 32 + j * 16 + lr) * 64 + ((kk * 32 + quad * 8) ^ rsw)];
    };

    f32x4 acc[8][2] = {};
    const int NT = K / 64;

    // prologue: tile0 {A0,A1,B} + tile1 A0 -> wait all but newest half
    stageH(0, 0); stageH(0, 1); stageH(0, 2); stageH(1, 0);
    asm volatile("s_waitcnt vmcnt(2)" ::: "memory");
    __builtin_amdgcn_s_barrier();

    s16x8 af[2][4], ag[2][4], bfr[2][2];
    for (int t = 0; t < NT; ++t) {
        const int par = t & 1;
        // ---- phase 0: (i 0-3) x (j 0-1) ----
#pragma unroll
        for (int kk = 0; kk < 2; kk++) {
#pragma unroll
            for (int i = 0; i < 4; i++) af[kk][i] = rdA(par, kk, i);
#pragma unroll
            for (int j = 0; j < 2; j++) bfr[kk][j] = rdB(par, kk, j);
        }
        if (t + 1 < NT) stageH(t + 1, 1);
        __builtin_amdgcn_s_barrier();
        asm volatile("s_waitcnt lgkmcnt(0)" ::: "memory");
        __builtin_amdgcn_s_setprio(1);
#pragma unroll
        for (int i = 0; i < 4; i++)
#pragma unroll
            for (int j = 0; j < 2; j++)
#pragma unroll
                for (int kk = 0; kk < 2; kk++)
                    acc[i][j] = MFMA(af[kk][i], bfr[kk][j], acc[i][j]);
        __builtin_amdgcn_s_setprio(0);
        __builtin_amdgcn_s_barrier();
        // ---- phase 1: (i 4-7) x (j 0-1); then stage t+2.A0 (parity par, safe) ----
#pragma unroll
        for (int kk = 0; kk < 2; kk++)
#pragma unroll
            for (int i = 0; i < 4; i++) ag[kk][i] = rdA(par, kk, 4 + i);
        if (t + 1 < NT) stageH(t + 1, 2);
        __builtin_amdgcn_s_barrier();
        asm volatile("s_waitcnt lgkmcnt(0)" ::: "memory");
        __builtin_amdgcn_s_setprio(1);
#pragma unroll
        for (int i = 0; i < 4; i++)
#pragma unroll
            for (int j = 0; j < 2; j++)
#pragma unroll
                for (int kk = 0; kk < 2; kk++)
                    acc[4 + i][j] = MFMA(ag[kk][i], bfr[kk][j], acc[4 + i][j]);
        __builtin_amdgcn_s_setprio(0);
        if (t + 2 < NT) stageH(t + 2, 0);
        if (t + 1 < NT) {
            if (t + 2 < NT) asm volatile("s_waitcnt vmcnt(2)" ::: "memory");
            else            asm volatile("s_waitcnt vmcnt(0)" ::: "memory");
            __builtin_amdgcn_s_barrier();
        }
    }

#pragma unroll
    for (int i = 0; i < 8; i++)
#pragma unroll
        for (int j = 0; j < 2; j++)
#pragma unroll
            for (int r = 0; r < 4; r++) {
                int row = m0 + mh * 128 + i * 16 + quad * 4 + r;
                int col = n0 + wnx * 32 + j * 16 + lr;
                if constexpr (sizeof(OutT) == 2)
                    C[(size_t)row * N + col] = f2bf(acc[i][j][r]);
                else
                    C[(size_t)row * N + col] = acc[i][j][r];
            }
}

// ---------------------------------------------------------------------------
// V transpose from fused qkv buffer (V at col 2560) -> vt (b,kvh, 64, S)
// ---------------------------------------------------------------------------
__global__ __launch_bounds__(256) void transpose_v(const us* __restrict__ qkv, us* __restrict__ vt) {
    __shared__ us tile[64][72];
    const int s0 = blockIdx.x * 64;
    const int bk = blockIdx.y;
    const int b = bk >> 3, kvh = bk & 7;
    const int t = threadIdx.x;
    const int r = t >> 3, cg = (t & 7) * 8;
#pragma unroll
    for (int p = 0; p < 2; p++) {
        int rr = r + p * 32;
        *(s16x8*)&tile[rr][cg] =
            *(const s16x8*)(qkv + (size_t)(b * SEQ + s0 + rr) * QKVN + 2560 + kvh * 64 + cg);
    }
    __syncthreads();
#pragma unroll
    for (int p = 0; p < 2; p++) {
        int d = r + p * 32;
        s16x8 val;
#pragma unroll
        for (int u = 0; u < 8; u++) val[u] = tile[cg + u][d];
        *(s16x8*)(vt + ((size_t)bk * VTR + d) * SEQ + s0 + cg) = val;
    }
}

// ---------------------------------------------------------------------------
// Causal flash attention — R6 4-tile structure + V phase-shift (proven
// neutral, kept). Occupancy RF-pinned at 2 waves/SIMD (unified VGPR+AGPR
// cap 256/wave; this kernel ~200). kf prefetch after last QK use; vf(kb+1)
// at loop bottom after PV. Both K/V global-latency hypotheses measured null
// -> remaining idle is structural; fixing it = swapped-QK rewrite (future).
// P-store scheme = R5-proven scalar stp + lgkmcnt(0). l via ones-col MFMA.
// ---------------------------------------------------------------------------
__global__ __launch_bounds__(256, 2) void flash_attn(const us* __restrict__ qkv,
                                                     const us* __restrict__ vt,
                                                     us* __restrict__ o) {
    __shared__ us P[4][4][16 * 72];           // [wave][tile]
    const int bh = blockIdx.y, b = bh >> 5, h = bh & 31, kvh = h >> 2;
    const int wave = threadIdx.x >> 6, lane = threadIdx.x & 63;
    const int quad = lane >> 4, lr = lane & 15;
    const int p = ((int)blockIdx.x + (int)(blockIdx.y >> 3)) & 7;
    const int qts[4] = {p, 15 - p, 16 + p, 31 - p};
    const us* kbase = qkv + (size_t)b * SEQ * QKVN + 2048 + kvh * 64;
    const us* vb = vt + (size_t)(b * 8 + kvh) * VTR * SEQ;
    const float QS = 0.125f * 1.44269504f;    // scale * log2(e)

    s16x8 onesb;
    const short ov = (lr == 0) ? (short)0x3F80 : (short)0;
#pragma unroll
    for (int j = 0; j < 8; j++) onesb[j] = ov;

    int q0[4];
    s16x8 qa[4][2];
#pragma unroll
    for (int t = 0; t < 4; t++) {
        q0[t] = qts[t] * 64 + wave * 16;
        const us* qb = qkv + (size_t)(b * SEQ + q0[t]) * QKVN + h * 64;
        qa[t][0] = *(const s16x8*)(qb + (size_t)lr * QKVN + quad * 8);
        qa[t][1] = *(const s16x8*)(qb + (size_t)lr * QKVN + 32 + quad * 8);
#pragma unroll
        for (int j = 0; j < 8; j++) {
            qa[t][0][j] = (short)f2bf(bf2f((us)qa[t][0][j]) * QS);
            qa[t][1][j] = (short)f2bf(bf2f((us)qa[t][1][j]) * QS);
        }
    }

    f32x4 oacc[4][5] = {};                    // per tile: [0..3]=O, [4] col0 = l
    s16x8 kf[8], vf[8];
    {
        const us* kp = kbase + (size_t)lr * QKVN;
#pragma unroll
        for (int nb = 0; nb < 4; nb++) {
            kf[2 * nb]     = *(const s16x8*)(kp + (size_t)nb * 16 * QKVN + quad * 8);
            kf[2 * nb + 1] = *(const s16x8*)(kp + (size_t)nb * 16 * QKVN + 32 + quad * 8);
        }
#pragma unroll
        for (int n = 0; n < 4; n++)
#pragma unroll
            for (int kc = 0; kc < 2; kc++)
                vf[n * 2 + kc] = *(const s16x8*)(vb + (size_t)(n * 16 + lr) * SEQ +
                                                 kc * 32 + quad * 8);
    }

    // QK for one tile -> sc; exp2 -> P[wave][t] (scalar b16 stores, R5-proven)
    auto qk_tile = [&](int t, f32x4* sc) {
#pragma unroll
        for (int nb = 0; nb < 4; nb++) {
            sc[nb] = f32x4{0.f, 0.f, 0.f, 0.f};
            sc[nb] = MFMA(qa[t][0], kf[2 * nb], sc[nb]);
            sc[nb] = MFMA(qa[t][1], kf[2 * nb + 1], sc[nb]);
        }
    };
    auto store_tile = [&](int t, const f32x4* sc, int kb) {
        us* Pt = &P[wave][t][0];
        if (kb == qts[t]) {                   // diagonal block: causal mask
#pragma unroll
            for (int nb = 0; nb < 4; nb++)
#pragma unroll
                for (int r = 0; r < 4; r++) {
                    int key = kb * 64 + nb * 16 + lr, row = q0[t] + quad * 4 + r;
                    float s = (key > row) ? -1e30f : sc[nb][r];
                    stp(&Pt[(quad * 4 + r) * 72 + nb * 16 + lr], exp2f(s));
                }
        } else {
#pragma unroll
            for (int nb = 0; nb < 4; nb++)
#pragma unroll
                for (int r = 0; r < 4; r++)
                    stp(&Pt[(quad * 4 + r) * 72 + nb * 16 + lr], exp2f(sc[nb][r]));
        }
    };

    const int kbmax = qts[3];
    for (int kb = 0; kb <= kbmax; kb++) {
        const bool a0 = (kb <= qts[0]), a1 = (kb <= qts[1]), a2 = (kb <= qts[2]);
        f32x4 sa[4], sb[4];
        // ---- QK pair 1 (tiles 0,1) with current kf ----
        if (a0) qk_tile(0, sa);
        if (a1) qk_tile(1, sb);
        if (a0) store_tile(0, sa, kb);
        if (a1) store_tile(1, sb, kb);
        // ---- QK pair 2 (tiles 2,3) still with current kf ----
        if (a2) qk_tile(2, sa);
        qk_tile(3, sb);                       // tile 3 always active
        // ---- kf prefetch for kb+1 (kf now dead until next iteration) ----
        if (kb < kbmax) {
            const us* kp = kbase + (size_t)((kb + 1) * 64 + lr) * QKVN;
#pragma unroll
            for (int nb = 0; nb < 4; nb++) {
                kf[2 * nb]     = *(const s16x8*)(kp + (size_t)nb * 16 * QKVN + quad * 8);
                kf[2 * nb + 1] = *(const s16x8*)(kp + (size_t)nb * 16 * QKVN + 32 + quad * 8);
            }
        }
        if (a2) store_tile(2, sa, kb);
        store_tile(3, sb, kb);
        asm volatile("s_waitcnt lgkmcnt(0)" ::: "memory");   // wave-private tiles
        // ---- PV for all active tiles, shared vf (loaded one iter ahead) ----
        __builtin_amdgcn_s_setprio(1);
#pragma unroll
        for (int t = 0; t < 4; t++) {
            if (kb <= qts[t]) {
#pragma unroll
                for (int kc = 0; kc < 2; kc++) {
                    s16x8 pa = *(const s16x8*)&P[wave][t][lr * 72 + kc * 32 + quad * 8];
#pragma unroll
                    for (int n = 0; n < 4; n++)
                        oacc[t][n] = MFMA(pa, vf[n * 2 + kc], oacc[t][n]);
                    oacc[t][4] = MFMA(pa, onesb, oacc[t][4]);
                }
            }
        }
        __builtin_amdgcn_s_setprio(0);
        // ---- vf load for kb+1 (vf dead after PV; full next-QK-phase cover) ----
        if (kb < kbmax) {
#pragma unroll
            for (int n = 0; n < 4; n++)
#pragma unroll
                for (int kc = 0; kc < 2; kc++)
                    vf[n * 2 + kc] = *(const s16x8*)(vb + (size_t)(n * 16 + lr) * SEQ +
                                                     (kb + 1) * 64 + kc * 32 + quad * 8);
        }
    }

#pragma unroll
    for (int t = 0; t < 4; t++)
#pragma unroll
        for (int r = 0; r < 4; r++) {
            float l = __shfl(oacc[t][4][r], lane & 48);
            float li = 1.0f / l;
#pragma unroll
            for (int n = 0; n < 4; n++)
                o[(size_t)(b * SEQ + q0[t] + quad * 4 + r) * DM + h * 64 + n * 16 + lr] =
                    f2bf(oacc[t][n][r] * li);
        }
}

// ---------------------------------------------------------------------------
extern "C" void kernel_launch(void* const* d_in, const int* in_sizes, int n_in,
                              void* d_out, int out_size, void* d_ws, size_t ws_size,
                              hipStream_t stream) {
    const float* x  = (const float*)d_in[0];
    const float* wq = (const float*)d_in[1];
    const float* wk = (const float*)d_in[2];
    const float* wv = (const float*)d_in[3];
    const float* wo = (const float*)d_in[4];
    float* out = (float*)d_out;

    char* ws = (char*)d_ws;
    const size_t MB = 1024 * 1024;
    us* xb     = (us*)(ws + 0 * MB);    // 16 MiB; reused as abuf (flash out)
    us* abuf   = (us*)(ws + 0 * MB);
    us* wqkvb  = (us*)(ws + 16 * MB);   // 12 MiB (wq|wk|wv) — contiguous with wob
    us* wob    = (us*)(ws + 28 * MB);   // 8 MiB
    us* qkvbuf = (us*)(ws + 36 * MB);   // 24 MiB (4096 x 3072)
    us* vtbuf  = (us*)(ws + 60 * MB);   // 4 MiB

    dim3 blk(256);
    cvt_all<<<dim3(18432), blk, 0, stream>>>(x, wq, wk, wv, wo, xb, wqkvb);

    gemm_bt2<us, true><<<dim3(16, 12), dim3(512), 0, stream>>>(xb, wqkvb, qkvbuf, 4096, 3072, 2048);
    transpose_v<<<dim3(32, 16), blk, 0, stream>>>(qkvbuf, vtbuf);
    flash_attn<<<dim3(8, 64), blk, 0, stream>>>(qkvbuf, vtbuf, abuf);
    gemm_bt2n<float><<<dim3(16, 16), dim3(512), 0, stream>>>(abuf, wob, out, 4096, 2048, 2048);
}